// Round 9
// baseline (4340.785 us; speedup 1.0000x reference)
//
#include <hip/hip_runtime.h>
#include <hip/hip_bf16.h>
#include <cmath>

#define NLAYERS 12
#define NHEADS  12
#define DM      768
#define VOCAB   50257
#define TSEQ    1024
#define BT      4096   // B*T
#define NCHUNK  786    // ceil(VOCAB/64) col-chunks for loss partials

typedef __attribute__((ext_vector_type(4))) float f32x4;
typedef __attribute__((ext_vector_type(8))) short bf16x8;
typedef __attribute__((ext_vector_type(4))) short s16x4;

typedef __hip_bfloat16 bf16;

#define MFMA16(a, b, c) __builtin_amdgcn_mfma_f32_16x16x32_bf16(a, b, c, 0, 0, 0)

// ---------------- helpers ----------------
__device__ __forceinline__ void gload16(const void* g, void* l) {
    __builtin_amdgcn_global_load_lds(
        (const __attribute__((address_space(1))) void*)g,
        (__attribute__((address_space(3))) void*)l, 16, 0, 0);
}

// raw s_barrier with compiler memory fences (no forced vmcnt(0) drain)
__device__ __forceinline__ void wg_barrier() {
    asm volatile("" ::: "memory");
    __builtin_amdgcn_s_barrier();
    asm volatile("" ::: "memory");
}

__device__ __forceinline__ float gelu_tanh(float v) {
    float u = 0.7978845608028654f * (v + 0.044715f * v * v * v);
    return 0.5f * v * (1.0f + tanhf(u));
}

__device__ __forceinline__ short f2bf(float f) {
    bf16 h = (bf16)f;
    return *reinterpret_cast<short*>(&h);
}

struct ushort4s { short a, b, c, d; };

// ---------------- weight prep ----------------
__global__ void transpose_bf16_kernel(const float* __restrict__ in, bf16* __restrict__ out,
                                      int K, int N) {
    __shared__ float tile[32][33];
    size_t lofs = (size_t)blockIdx.z * K * N;
    int k0 = blockIdx.y * 32, n0 = blockIdx.x * 32;
    int tx = threadIdx.x, ty = threadIdx.y;      // 32x8
#pragma unroll
    for (int i = 0; i < 32; i += 8)
        tile[ty + i][tx] = in[lofs + (size_t)(k0 + ty + i) * N + n0 + tx];
    __syncthreads();
#pragma unroll
    for (int i = 0; i < 32; i += 8)
        out[lofs + (size_t)(n0 + ty + i) * K + k0 + tx] = (bf16)tile[tx][ty + i];
}

__global__ void tobf16_kernel(const float* __restrict__ in, bf16* __restrict__ out, size_t n) {
    size_t i = (size_t)blockIdx.x * 256 + threadIdx.x;
    if (i < n) out[i] = (bf16)in[i];
}

// ---------------- embedding (fp32 residual stream, float4) ----------------
__global__ void embed_kernel(const int* __restrict__ inp, const float* __restrict__ wte,
                             const float* __restrict__ wpe, float* __restrict__ x) {
    int idx = blockIdx.x * 256 + threadIdx.x;    // over BT*DM/4
    int m = idx / (DM / 4), c4 = idx % (DM / 4);
    int tok = inp[m];
    int t = m & (TSEQ - 1);
    float4 a = reinterpret_cast<const float4*>(wte)[(size_t)tok * (DM / 4) + c4];
    float4 b = reinterpret_cast<const float4*>(wpe)[(size_t)t * (DM / 4) + c4];
    float4 o = {a.x + b.x, a.y + b.y, a.z + b.z, a.w + b.w};
    reinterpret_cast<float4*>(x)[idx] = o;
}

// ---------------- layernorm: fp32 in -> bf16 out (vectorized) ----------------
__global__ __launch_bounds__(256) void ln_kernel(const float* __restrict__ x,
                                                 const float* __restrict__ w,
                                                 const float* __restrict__ b,
                                                 bf16* __restrict__ y) {
    int row = blockIdx.x, tid = threadIdx.x;     // 256 threads, 192 active for data
    const float4* xr = reinterpret_cast<const float4*>(x + (size_t)row * DM);
    float4 v = {0.f, 0.f, 0.f, 0.f};
    float s = 0.f, q = 0.f;
    if (tid < 192) {
        v = xr[tid];
        s = v.x + v.y + v.z + v.w;
        q = v.x * v.x + v.y * v.y + v.z * v.z + v.w * v.w;
    }
#pragma unroll
    for (int o = 1; o < 64; o <<= 1) { s += __shfl_xor(s, o); q += __shfl_xor(q, o); }
    __shared__ float ss[4], qq[4];
    if ((tid & 63) == 0) { ss[tid >> 6] = s; qq[tid >> 6] = q; }
    __syncthreads();
    s = ss[0] + ss[1] + ss[2] + ss[3];
    q = qq[0] + qq[1] + qq[2] + qq[3];
    float mu  = s * (1.0f / DM);
    float var = q * (1.0f / DM) - mu * mu;
    float inv = rsqrtf(var + 1e-5f);
    if (tid < 192) {
        float4 wv = reinterpret_cast<const float4*>(w)[tid];
        float4 bv = reinterpret_cast<const float4*>(b)[tid];
        ushort4s o;
        o.a = f2bf((v.x - mu) * inv * wv.x + bv.x);
        o.b = f2bf((v.y - mu) * inv * wv.y + bv.y);
        o.c = f2bf((v.z - mu) * inv * wv.z + bv.z);
        o.d = f2bf((v.w - mu) * inv * wv.w + bv.w);
        *reinterpret_cast<ushort4s*>(y + (size_t)row * DM + tid * 4) = o;
    }
}

#define GF_GELU    1
#define GF_OBF16   2
#define GF_CLAMP   4
#define GF_PARTIAL 8

// ---------------- 128x128 2-phase GEMM (qkv / proj / fc / fc2) ----------------
template<int FLAGS, int TAG>
__global__ __launch_bounds__(256) void gemm_k(
    const bf16* __restrict__ A, const bf16* __restrict__ Bt,
    const float* __restrict__ bias, const float* __restrict__ resid,
    void* __restrict__ C, float2* __restrict__ partials,
    int M, int N, int K) {
    __shared__ short ldsA[2][128 * 32];
    __shared__ short ldsB[2][128 * 32];
    int tid = threadIdx.x;
    int lane = tid & 63, w = tid >> 6;
    int wm = w >> 1, wn = w & 1;
    int r = lane & 15, kq = lane >> 4;
    int bm = blockIdx.x * 128, bn = blockIdx.y * 128;

    f32x4 acc[4][4] = {};

    auto stage = [&](int buf, int k0) {
#pragma unroll
        for (int i = 0; i < 2; ++i) {
            int chunk = i * 256 + tid;           // 16B chunk id = row*4 + dest granule
            int row = chunk >> 2;
            int gs = (chunk & 3) ^ ((row >> 1) & 3);   // swizzled source granule
            const bf16* ga = A + (size_t)(bm + row) * K + k0 + gs * 8;
            gload16(ga, &ldsA[buf][(i * 256 + w * 64) * 8]);
            int brow = bn + row;
            if (FLAGS & GF_CLAMP) brow = min(brow, N - 1);
            const bf16* gb = Bt + (size_t)brow * K + k0 + gs * 8;
            gload16(gb, &ldsB[buf][(i * 256 + w * 64) * 8]);
        }
    };
    auto compute = [&](int buf) {
        bf16x8 af[4], bfr[4];
#pragma unroll
        for (int m = 0; m < 4; ++m) {
            int row = wm * 64 + m * 16 + r;
            af[m] = *reinterpret_cast<bf16x8*>(&ldsA[buf][row * 32 + (kq ^ ((row >> 1) & 3)) * 8]);
        }
#pragma unroll
        for (int n = 0; n < 4; ++n) {
            int row = wn * 64 + n * 16 + r;
            bfr[n] = *reinterpret_cast<bf16x8*>(&ldsB[buf][row * 32 + (kq ^ ((row >> 1) & 3)) * 8]);
        }
#pragma unroll
        for (int m = 0; m < 4; ++m)
#pragma unroll
            for (int n = 0; n < 4; ++n)
                acc[m][n] = MFMA16(af[m], bfr[n], acc[m][n]);
    };

    stage(0, 0);
    __syncthreads();
    int buf = 0;
    for (int k0 = 32; k0 < K; k0 += 32) {
        stage(buf ^ 1, k0);
        compute(buf);
        __syncthreads();
        buf ^= 1;
    }
    compute(buf);

    int row0 = bm + wm * 64, col0 = bn + wn * 64;
#pragma unroll
    for (int m = 0; m < 4; ++m) {
#pragma unroll
        for (int n = 0; n < 4; ++n) {
            int col = col0 + n * 16 + r;
            if (col < N) {
#pragma unroll
                for (int rr = 0; rr < 4; ++rr) {
                    int row = row0 + m * 16 + kq * 4 + rr;
                    float v = acc[m][n][rr];
                    if (bias) v += bias[col];
                    if (FLAGS & GF_GELU) v = gelu_tanh(v);
                    if (resid) v += resid[(size_t)row * N + col];
                    if (FLAGS & GF_OBF16) ((bf16*)C)[(size_t)row * N + col] = (bf16)v;
                    else                  ((float*)C)[(size_t)row * N + col] = v;
                }
            }
        }
    }
}

// ---------------- 256x256 pipelined 8-phase GEMM (lm_head) ----------------
// BK=64, 8 waves (2M x 4N). Per K-tile 4 phases; frag ds_reads issued ONE PHASE
// EARLY (before the barrier preceding their MFMA) so LDS latency hides under the
// barrier + other waves' MFMA (m196/m201 interleave lever). vmcnt(0) only at p2
// (tile t+1's loads were issued 2 phases earlier); bar_2 publishes residency so
// p3 pre-reads tile t+1's phase-0 frags. Granule XOR swizzle both sides.
template<int FLAGS, int TAG>
__global__ __launch_bounds__(512, 2) void gemm256_8p(
    const bf16* __restrict__ A, const bf16* __restrict__ Bt,
    const float* __restrict__ bias, const float* __restrict__ resid,
    void* __restrict__ C, float2* __restrict__ partials,
    int M, int N, int K) {
    __shared__ short lds[2][2][256 * 64];        // [buf][A=0/B=1][row*64 + granule*8]
    int tid = threadIdx.x;                       // 0..511
    int lane = tid & 63, w = tid >> 6;
    int wm = w >> 2, wn = w & 3;                 // 2 x 4 waves
    int r = lane & 15, kq = lane >> 4;
    int bm = blockIdx.x * 256, bn = blockIdx.y * 256;

    f32x4 acc[8][4] = {};

    auto stage_half = [&](int buf, int kt, int half) {
        int mat = half >> 1;
        int hrow = (half & 1) * 128;
        const bf16* src = mat ? Bt : A;
        int base = mat ? bn : bm;
#pragma unroll
        for (int i = 0; i < 2; ++i) {
            int chunk = i * 512 + tid;               // 0..1023 = lrow*8 + dest granule
            int lrow = hrow + (chunk >> 3);
            int gsrc = (chunk & 7) ^ (lrow & 7);     // inverse-swizzled source granule
            int grow = base + lrow;
            if (mat && (FLAGS & GF_CLAMP)) grow = min(grow, N - 1);
            gload16(src + (size_t)grow * K + kt * 64 + gsrc * 8,
                    &lds[buf][mat][hrow * 64 + chunk * 8]);
        }
    };

    struct Frags { bf16x8 a[4][2]; bf16x8 b[2][2]; };

    auto ld_frags = [&](int buf, int p, Frags& F) {
        int mh = p >> 1, nh = p & 1;
#pragma unroll
        for (int n2 = 0; n2 < 2; ++n2) {
            int row = wn * 64 + (nh * 2 + n2) * 16 + r;
#pragma unroll
            for (int kk = 0; kk < 2; ++kk)
                F.b[n2][kk] = *reinterpret_cast<bf16x8*>(
                    &lds[buf][1][row * 64 + ((kk * 4 + kq) ^ (row & 7)) * 8]);
        }
#pragma unroll
        for (int m2 = 0; m2 < 4; ++m2) {
            int row = wm * 128 + (mh * 4 + m2) * 16 + r;
#pragma unroll
            for (int kk = 0; kk < 2; ++kk)
                F.a[m2][kk] = *reinterpret_cast<bf16x8*>(
                    &lds[buf][0][row * 64 + ((kk * 4 + kq) ^ (row & 7)) * 8]);
        }
    };

    auto do_mfma = [&](int p, Frags& F) {
        int mh = p >> 1, nh = p & 1;
        __builtin_amdgcn_s_setprio(1);
#pragma unroll
        for (int m2 = 0; m2 < 4; ++m2)
#pragma unroll
            for (int n2 = 0; n2 < 2; ++n2)
#pragma unroll
                for (int kk = 0; kk < 2; ++kk)
                    acc[mh * 4 + m2][nh * 2 + n2] =
                        MFMA16(F.a[m2][kk], F.b[n2][kk], acc[mh * 4 + m2][nh * 2 + n2]);
        __builtin_amdgcn_s_setprio(0);
    };

    const int NT = K / 64;
    stage_half(0, 0, 0); stage_half(0, 0, 1); stage_half(0, 0, 2); stage_half(0, 0, 3);
    asm volatile("s_waitcnt vmcnt(0)" ::: "memory");
    wg_barrier();                                // tile 0 resident for all waves
    Frags cur, nxt;
    ld_frags(0, 0, cur);

    for (int t = 0; t < NT; ++t) {
        int buf = t & 1;
        bool more = (t + 1 < NT);
        // p0: MFMA(q0, cur) | stage t+1 A halves | preload q1 frags
        do_mfma(0, cur);
        if (more) { stage_half(buf ^ 1, t + 1, 0); stage_half(buf ^ 1, t + 1, 1); }
        ld_frags(buf, 1, nxt);
        wg_barrier();
        // p1: MFMA(q1, nxt) | stage t+1 B halves | preload q2 frags
        do_mfma(1, nxt);
        if (more) { stage_half(buf ^ 1, t + 1, 2); stage_half(buf ^ 1, t + 1, 3); }
        ld_frags(buf, 2, cur);
        wg_barrier();
        // p2: MFMA(q2, cur) | vmcnt(0): this wave's t+1 loads done | preload q3
        do_mfma(2, cur);
        if (more) asm volatile("s_waitcnt vmcnt(0)" ::: "memory");
        ld_frags(buf, 3, nxt);
        wg_barrier();                            // bar_2: buf^1 resident for ALL waves
        // p3: MFMA(q3, nxt) | preload next tile's q0 frags (safe after bar_2)
        do_mfma(3, nxt);
        if (more) ld_frags(buf ^ 1, 0, cur);
        wg_barrier();
    }

    int row0 = bm + wm * 128, col0 = bn + wn * 64;
#pragma unroll
    for (int m = 0; m < 8; ++m) {
#pragma unroll
        for (int n = 0; n < 4; ++n) {
            int col = col0 + n * 16 + r;
            if (col < N) {
#pragma unroll
                for (int rr = 0; rr < 4; ++rr) {
                    int row = row0 + m * 16 + kq * 4 + rr;
                    float v = acc[m][n][rr];
                    if (bias) v += bias[col];
                    if (FLAGS & GF_GELU) v = gelu_tanh(v);
                    if (resid) v += resid[(size_t)row * N + col];
                    if (FLAGS & GF_OBF16) ((bf16*)C)[(size_t)row * N + col] = (bf16)v;
                    else                  ((float*)C)[(size_t)row * N + col] = v;
                }
            }
        }
    }

    if (FLAGS & GF_PARTIAL) {
        int chunk = (bn >> 6) + wn;              // 64-col chunk index
        if (chunk < NCHUNK) {
#pragma unroll
            for (int m = 0; m < 8; ++m) {
#pragma unroll
                for (int rr = 0; rr < 4; ++rr) {
                    float vals[4], mx = -INFINITY;
#pragma unroll
                    for (int n = 0; n < 4; ++n) {
                        int col = col0 + n * 16 + r;
                        float v = (col < N) ? acc[m][n][rr] : -INFINITY;
                        vals[n] = v;
                        mx = fmaxf(mx, v);
                    }
#pragma unroll
                    for (int o = 1; o < 16; o <<= 1) mx = fmaxf(mx, __shfl_xor(mx, o));
                    float sum = 0.f;
#pragma unroll
                    for (int n = 0; n < 4; ++n)
                        if (vals[n] > -INFINITY) sum += __expf(vals[n] - mx);
#pragma unroll
                    for (int o = 1; o < 16; o <<= 1) sum += __shfl_xor(sum, o);
                    if (r == 0) {
                        int row = row0 + m * 16 + kq * 4 + rr;
                        partials[(size_t)row * NCHUNK + chunk] = make_float2(mx, sum);
                    }
                }
            }
        }
    }
}

// ---------------- flash attention (bf16 MFMA, online softmax) ----------------
// QBLK=64 (4 waves x 16 q-rows), KVBLK=128. K and V^T both granule-XOR-swizzled;
// V transposed via 4 row loads + 8 packed ds_write_b64 per thread.
__global__ __launch_bounds__(256) void flash_attn_kernel(const bf16* __restrict__ qkv,
                                                         bf16* __restrict__ ctx) {
    __shared__ short Ks[128 * 64];       // K tile [kv][64], granule ^= row&7
    __shared__ short Vt[64 * 128];       // V^T tile [d][128 kv], granule ^= d&7
    __shared__ short Ps[4][16][132];     // per-wave P tile [qrow][kv], padded stride

    int tid = threadIdx.x, lane = tid & 63, w = tid >> 6;
    int r = lane & 15, kq = lane >> 4;
    int q0 = blockIdx.x * 64;
    int bh = blockIdx.y;
    int b = bh / NHEADS, h = bh % NHEADS;
    const int RS = 3 * DM;               // qkv row stride

    const bf16* qbase = qkv + (size_t)(b * TSEQ + q0 + w * 16 + r) * RS + h * 64;
    bf16x8 qf[2];
    qf[0] = *reinterpret_cast<const bf16x8*>(qbase + kq * 8);
    qf[1] = *reinterpret_cast<const bf16x8*>(qbase + 32 + kq * 8);

    f32x4 of[4] = {};
    float mrow[4] = {-INFINITY, -INFINITY, -INFINITY, -INFINITY};
    float lrow[4] = {};

    int ntiles = (blockIdx.x >> 1) + 1;
    for (int t = 0; t < ntiles; ++t) {
        int kv0 = t * 128;
        __syncthreads();
        // ---- stage K [128][64] via global_load_lds, source-granule swizzled ----
        const bf16* kbase = qkv + (size_t)(b * TSEQ + kv0) * RS + DM + h * 64;
#pragma unroll
        for (int i = 0; i < 4; ++i) {
            int chunk = i * 256 + tid;
            int row = chunk >> 3, cp = chunk & 7;
            int csrc = cp ^ (row & 7);
            gload16(kbase + (size_t)row * RS + csrc * 8, Ks + chunk * 8);
        }
        // ---- stage V^T: 4 row loads -> 8 packed b64 LDS writes per thread ----
        const bf16* vbase = qkv + (size_t)(b * TSEQ + kv0) * RS + 2 * DM + h * 64;
        {
            int kvq = tid >> 3;              // 0..31 -> kv rows kvq*4 .. kvq*4+3
            int d0 = (tid & 7) * 8;
            bf16x8 v0 = *reinterpret_cast<const bf16x8*>(vbase + (size_t)(kvq * 4 + 0) * RS + d0);
            bf16x8 v1 = *reinterpret_cast<const bf16x8*>(vbase + (size_t)(kvq * 4 + 1) * RS + d0);
            bf16x8 v2 = *reinterpret_cast<const bf16x8*>(vbase + (size_t)(kvq * 4 + 2) * RS + d0);
            bf16x8 v3 = *reinterpret_cast<const bf16x8*>(vbase + (size_t)(kvq * 4 + 3) * RS + d0);
            int lg = kvq >> 1, half = kvq & 1;
#pragma unroll
            for (int j = 0; j < 8; ++j) {
                int d = d0 + j;
                int phys = lg ^ (d & 7);
                s16x4 pk = {v0[j], v1[j], v2[j], v3[j]};
                *reinterpret_cast<s16x4*>(&Vt[d * 128 + phys * 8 + half * 4]) = pk;
            }
        }
        __syncthreads();

        // ---- QK^T: 16 MFMA ----
        f32x4 sf[8];
#pragma unroll
        for (int n = 0; n < 8; ++n) sf[n] = (f32x4){0.f, 0.f, 0.f, 0.f};
        __builtin_amdgcn_s_setprio(1);
#pragma unroll
        for (int n = 0; n < 8; ++n) {
            int row = n * 16 + r;
#pragma unroll
            for (int kt = 0; kt < 2; ++kt) {
                int gran = (kt * 4 + kq) ^ (row & 7);
                bf16x8 kf = *reinterpret_cast<bf16x8*>(&Ks[row * 64 + gran * 8]);
                sf[n] = MFMA16(qf[kt], kf, sf[n]);
            }
        }
        __builtin_amdgcn_s_setprio(0);

        // ---- online softmax over 128 cols ----
        bool diag = (kv0 + 128 > q0);
        float alpha[4];
#pragma unroll
        for (int rr = 0; rr < 4; ++rr) {
            int qrow = q0 + w * 16 + kq * 4 + rr;
            float vals[8];
            float mx = mrow[rr];
#pragma unroll
            for (int n = 0; n < 8; ++n) {
                float v = sf[n][rr] * 0.125f;
                if (diag && (kv0 + n * 16 + r) > qrow) v = -INFINITY;
                vals[n] = v;
                mx = fmaxf(mx, v);
            }
#pragma unroll
            for (int o = 1; o < 16; o <<= 1) mx = fmaxf(mx, __shfl_xor(mx, o));
            float al = __expf(mrow[rr] - mx);
            float sum = 0.f;
#pragma unroll
            for (int n = 0; n < 8; ++n) {
                float p = __expf(vals[n] - mx);
                vals[n] = p;
                sum += p;
            }
#pragma unroll
            for (int o = 1; o < 16; o <<= 1) sum += __shfl_xor(sum, o);
            mrow[rr] = mx;
            lrow[rr] = lrow[rr] * al + sum;
            alpha[rr] = al;
#pragma unroll
            for (int n = 0; n < 8; ++n) Ps[w][kq * 4 + rr][n * 16 + r] = f2bf(vals[n]);
        }
#pragma unroll
        for (int n = 0; n < 4; ++n)
#pragma unroll
            for (int rr = 0; rr < 4; ++rr) of[n][rr] *= alpha[rr];

        // ---- PV: 16 MFMA, V^T frags via swizzled reads ----
        __builtin_amdgcn_s_setprio(1);
#pragma unroll
        for (int kt = 0; kt < 4; ++kt) {
            bf16x8 pa = *reinterpret_cast<bf16x8*>(&Ps[w][r][kt * 32 + kq * 8]);
#pragma unroll
            for (int n = 0; n < 4; ++n) {
                int row = n * 16 + r;
                int gran = (kt * 4 + kq) ^ (row & 7);
                bf16x8 vf = *reinterpret_cast<bf16x8*>(&Vt[row * 128 + gran * 8]);
                of[n] = MFMA16(pa, vf, of[n]);
            }
        }
        __builtin_amdgcn_s_setprio(0);
    }

    // ---- epilogue ----
#pragma unroll
    for (int rr = 0; rr < 4; ++rr) {
        float inv = 1.0f / lrow[rr];
        int qrow = q0 + w * 16 + kq * 4 + rr;
        bf16* cb = ctx + (size_t)(b * TSEQ + qrow) * DM + h * 64;
#pragma unroll
        for (int n = 0; n < 4; ++n) cb[n * 16 + r] = (bf16)(of[n][rr] * inv);
    }
}

// ---------------- loss: merge per-chunk partials ----------------
__global__ __launch_bounds__(256) void loss_reduce_kernel(const float2* __restrict__ partials,
                                                          const float* __restrict__ logits,
                                                          const int* __restrict__ target,
                                                          float* __restrict__ nll) {
    int row = blockIdx.x, tid = threadIdx.x;
    const float2* pr = partials + (size_t)row * NCHUNK;
    float m = -INFINITY, s = 0.f;
    for (int c = tid; c < NCHUNK; c += 256) {
        float2 p = pr[c];
        if (p.x > m) { s = s * __expf(m - p.x) + p.y; m = p.x; }
        else         { s += p.y * __expf(p.x - m); }
    }
    __shared__ float sm[256], ssum[256];
    sm[tid] = m; ssum[tid] = s; __syncthreads();
    for (int o = 128; o; o >>= 1) {
        if (tid < o) {
            float m2 = sm[tid + o], s2 = ssum[tid + o];
            float mm = fmaxf(sm[tid], m2);
            ssum[tid] = ssum[tid] * __expf(sm[tid] - mm) + s2 * __expf(m2 - mm);
            sm[tid] = mm;
        }
        __syncthreads();
    }
    if (tid == 0) {
        float lse = sm[0] + logf(ssum[0]);
        nll[row] = lse - logits[(size_t)row * VOCAB + target[row]];
    }
}

__global__ void loss2_kernel(const float* __restrict__ nll, float* __restrict__ loss) {
    int tid = threadIdx.x;
    float s = 0.f;
    for (int i = tid; i < BT; i += 1024) s += nll[i];
    __shared__ float r[1024];
    r[tid] = s; __syncthreads();
    for (int o = 512; o; o >>= 1) { if (tid < o) r[tid] += r[tid + o]; __syncthreads(); }
    if (tid == 0) *loss = r[0] * (1.0f / BT);
}

// ---------------- launcher ----------------
extern "C" void kernel_launch(void* const* d_in, const int* in_sizes, int n_in,
                              void* d_out, int out_size, void* d_ws, size_t ws_size,
                              hipStream_t stream) {
    const int*   inp    = (const int*)  d_in[0];
    const int*   target = (const int*)  d_in[1];
    const float* wte    = (const float*)d_in[2];
    const float* wpe    = (const float*)d_in[3];
    const float* ln1_w  = (const float*)d_in[4];
    const float* ln1_b  = (const float*)d_in[5];
    const float* attn_w = (const float*)d_in[6];
    const float* attn_b = (const float*)d_in[7];
    const float* proj_w = (const float*)d_in[8];
    const float* proj_b = (const float*)d_in[9];
    const float* ln2_w  = (const float*)d_in[10];
    const float* ln2_b  = (const float*)d_in[11];
    const float* fc_w   = (const float*)d_in[12];
    const float* fc_b   = (const float*)d_in[13];
    const float* fc2_w  = (const float*)d_in[14];
    const float* fc2_b  = (const float*)d_in[15];
    const float* lnf_w  = (const float*)d_in[16];
    const float* lnf_b  = (const float*)d_in[17];
    float* out = (float*)d_out;

    char* p = (char*)d_ws;
    auto alloc = [&](size_t bytes) { char* q = p; p += (bytes + 255) & ~(size_t)255; return q; };
    float* x     = (float*)alloc((size_t)BT * DM * 4);
    float* nll   = (float*)alloc((size_t)BT * 4);
    bf16*  qkvb  = (bf16*) alloc((size_t)BT * 3 * DM * 2);
    bf16*  tmpb  = (bf16*) alloc((size_t)BT * DM * 2);
    bf16*  ctxb  = (bf16*) alloc((size_t)BT * DM * 2);
    bf16*  hb    = (bf16*) alloc((size_t)BT * 4 * DM * 2);
    bf16*  wteb  = (bf16*) alloc((size_t)VOCAB * DM * 2);
    bf16*  wqkvT = (bf16*) alloc((size_t)NLAYERS * 3 * DM * DM * 2);
    bf16*  wprojT= (bf16*) alloc((size_t)NLAYERS * DM * DM * 2);
    bf16*  wfcT  = (bf16*) alloc((size_t)NLAYERS * 4 * DM * DM * 2);
    bf16*  wfc2T = (bf16*) alloc((size_t)NLAYERS * 4 * DM * DM * 2);
    // loss partials (25.8 MB) alias the ctxb+hb region (31.5 MB, dead after layer loop)
    float2* partials = (float2*)ctxb;

    dim3 tb(32, 8);
    transpose_bf16_kernel<<<dim3(3 * DM / 32, DM / 32, NLAYERS), tb, 0, stream>>>(attn_w, wqkvT, DM, 3 * DM);
    transpose_bf16_kernel<<<dim3(DM / 32, DM / 32, NLAYERS), tb, 0, stream>>>(proj_w, wprojT, DM, DM);
    transpose_bf16_kernel<<<dim3(4 * DM / 32, DM / 32, NLAYERS), tb, 0, stream>>>(fc_w, wfcT, DM, 4 * DM);
    transpose_bf16_kernel<<<dim3(DM / 32, 4 * DM / 32, NLAYERS), tb, 0, stream>>>(fc2_w, wfc2T, 4 * DM, DM);
    {
        size_t n = (size_t)VOCAB * DM;
        tobf16_kernel<<<(unsigned)((n + 255) / 256), 256, 0, stream>>>(wte, wteb, n);
    }

    embed_kernel<<<BT * DM / 4 / 256, 256, 0, stream>>>(inp, wte, wpe, x);

    for (int i = 0; i < NLAYERS; ++i) {
        ln_kernel<<<BT, 256, 0, stream>>>(x, ln1_w + i * DM, ln1_b + i * DM, tmpb);
        gemm_k<GF_OBF16, 0><<<dim3(BT / 128, 3 * DM / 128), 256, 0, stream>>>(
            tmpb, wqkvT + (size_t)i * 3 * DM * DM, attn_b + i * 3 * DM, nullptr,
            qkvb, nullptr, BT, 3 * DM, DM);
        flash_attn_kernel<<<dim3(TSEQ / 64, 4 * NHEADS), 256, 0, stream>>>(qkvb, ctxb);
        gemm_k<0, 1><<<dim3(BT / 128, DM / 128), 256, 0, stream>>>(
            ctxb, wprojT + (size_t)i * DM * DM, proj_b + i * DM, x,
            x, nullptr, BT, DM, DM);
        ln_kernel<<<BT, 256, 0, stream>>>(x, ln2_w + i * DM, ln2_b + i * DM, tmpb);
        gemm_k<GF_GELU | GF_OBF16, 2><<<dim3(BT / 128, 4 * DM / 128), 256, 0, stream>>>(
            tmpb, wfcT + (size_t)i * 4 * DM * DM, fc_b + i * 4 * DM, nullptr,
            hb, nullptr, BT, 4 * DM, DM);
        gemm_k<0, 3><<<dim3(BT / 128, DM / 128), 256, 0, stream>>>(
            hb, wfc2T + (size_t)i * 4 * DM * DM, fc2_b + i * DM, x,
            x, nullptr, BT, DM, 4 * DM);
    }

    ln_kernel<<<BT, 256, 0, stream>>>(x, lnf_w, lnf_b, tmpb);
    gemm256_8p<GF_CLAMP | GF_PARTIAL, 4><<<dim3(BT / 256, (VOCAB + 255) / 256), 512, 0, stream>>>(
        tmpb, wteb, nullptr, nullptr, out, partials, BT, VOCAB, DM);
    loss_reduce_kernel<<<BT, 256, 0, stream>>>(partials, out, target, nll);
    loss2_kernel<<<1, 1024, 0, stream>>>(nll, out + (size_t)out_size - 1);
}

// Round 10
// 4261.625 us; speedup vs baseline: 1.0186x; 1.0186x over previous
//
#include <hip/hip_runtime.h>
#include <hip/hip_bf16.h>
#include <cmath>

#define NLAYERS 12
#define NHEADS  12
#define DM      768
#define VOCAB   50257
#define TSEQ    1024
#define BT      4096   // B*T
#define NCHUNK  786    // ceil(VOCAB/64) col-chunks for loss partials

typedef __attribute__((ext_vector_type(4))) float f32x4;
typedef __attribute__((ext_vector_type(8))) short bf16x8;
typedef __attribute__((ext_vector_type(4))) short s16x4;

typedef __hip_bfloat16 bf16;

#define MFMA16(a, b, c) __builtin_amdgcn_mfma_f32_16x16x32_bf16(a, b, c, 0, 0, 0)

// ---------------- helpers ----------------
__device__ __forceinline__ void gload16(const void* g, void* l) {
    __builtin_amdgcn_global_load_lds(
        (const __attribute__((address_space(1))) void*)g,
        (__attribute__((address_space(3))) void*)l, 16, 0, 0);
}

// raw s_barrier with compiler memory fences (no forced vmcnt(0) drain)
__device__ __forceinline__ void wg_barrier() {
    asm volatile("" ::: "memory");
    __builtin_amdgcn_s_barrier();
    asm volatile("" ::: "memory");
}

__device__ __forceinline__ float gelu_tanh(float v) {
    float u = 0.7978845608028654f * (v + 0.044715f * v * v * v);
    return 0.5f * v * (1.0f + tanhf(u));
}

__device__ __forceinline__ short f2bf(float f) {
    bf16 h = (bf16)f;
    return *reinterpret_cast<short*>(&h);
}

struct ushort4s { short a, b, c, d; };

// ---------------- weight prep ----------------
__global__ void transpose_bf16_kernel(const float* __restrict__ in, bf16* __restrict__ out,
                                      int K, int N) {
    __shared__ float tile[32][33];
    size_t lofs = (size_t)blockIdx.z * K * N;
    int k0 = blockIdx.y * 32, n0 = blockIdx.x * 32;
    int tx = threadIdx.x, ty = threadIdx.y;      // 32x8
#pragma unroll
    for (int i = 0; i < 32; i += 8)
        tile[ty + i][tx] = in[lofs + (size_t)(k0 + ty + i) * N + n0 + tx];
    __syncthreads();
#pragma unroll
    for (int i = 0; i < 32; i += 8)
        out[lofs + (size_t)(n0 + ty + i) * K + k0 + tx] = (bf16)tile[tx][ty + i];
}

__global__ void tobf16_kernel(const float* __restrict__ in, bf16* __restrict__ out, size_t n) {
    size_t i = (size_t)blockIdx.x * 256 + threadIdx.x;
    if (i < n) out[i] = (bf16)in[i];
}

// ---------------- embedding (fp32 residual stream, float4) ----------------
__global__ void embed_kernel(const int* __restrict__ inp, const float* __restrict__ wte,
                             const float* __restrict__ wpe, float* __restrict__ x) {
    int idx = blockIdx.x * 256 + threadIdx.x;    // over BT*DM/4
    int m = idx / (DM / 4), c4 = idx % (DM / 4);
    int tok = inp[m];
    int t = m & (TSEQ - 1);
    float4 a = reinterpret_cast<const float4*>(wte)[(size_t)tok * (DM / 4) + c4];
    float4 b = reinterpret_cast<const float4*>(wpe)[(size_t)t * (DM / 4) + c4];
    float4 o = {a.x + b.x, a.y + b.y, a.z + b.z, a.w + b.w};
    reinterpret_cast<float4*>(x)[idx] = o;
}

// ---------------- layernorm: one row per WAVE (no block sync) ----------------
__global__ __launch_bounds__(256) void ln_kernel(const float* __restrict__ x,
                                                 const float* __restrict__ w,
                                                 const float* __restrict__ b,
                                                 bf16* __restrict__ y) {
    int tid = threadIdx.x, wv = tid >> 6, lane = tid & 63;
    int row = blockIdx.x * 4 + wv;
    const float4* xr = reinterpret_cast<const float4*>(x + (size_t)row * DM);
    float4 v[3];
    float s = 0.f, q = 0.f;
#pragma unroll
    for (int j = 0; j < 3; ++j) {
        v[j] = xr[lane + 64 * j];
        s += v[j].x + v[j].y + v[j].z + v[j].w;
        q += v[j].x * v[j].x + v[j].y * v[j].y + v[j].z * v[j].z + v[j].w * v[j].w;
    }
#pragma unroll
    for (int o = 1; o < 64; o <<= 1) { s += __shfl_xor(s, o); q += __shfl_xor(q, o); }
    float mu  = s * (1.0f / DM);
    float var = q * (1.0f / DM) - mu * mu;
    float inv = rsqrtf(var + 1e-5f);
#pragma unroll
    for (int j = 0; j < 3; ++j) {
        int c4 = lane + 64 * j;
        float4 wv4 = reinterpret_cast<const float4*>(w)[c4];
        float4 bv4 = reinterpret_cast<const float4*>(b)[c4];
        ushort4s o;
        o.a = f2bf((v[j].x - mu) * inv * wv4.x + bv4.x);
        o.b = f2bf((v[j].y - mu) * inv * wv4.y + bv4.y);
        o.c = f2bf((v[j].z - mu) * inv * wv4.z + bv4.z);
        o.d = f2bf((v[j].w - mu) * inv * wv4.w + bv4.w);
        *reinterpret_cast<ushort4s*>(y + (size_t)row * DM + c4 * 4) = o;
    }
}

#define GF_GELU    1
#define GF_OBF16   2
#define GF_CLAMP   4
#define GF_PARTIAL 8

// ---------------- 128x128 2-phase GEMM (qkv / proj / fc / fc2) ----------------
template<int FLAGS, int TAG>
__global__ __launch_bounds__(256) void gemm_k(
    const bf16* __restrict__ A, const bf16* __restrict__ Bt,
    const float* __restrict__ bias, const float* __restrict__ resid,
    void* __restrict__ C, float2* __restrict__ partials,
    int M, int N, int K) {
    __shared__ short ldsA[2][128 * 32];
    __shared__ short ldsB[2][128 * 32];
    int tid = threadIdx.x;
    int lane = tid & 63, w = tid >> 6;
    int wm = w >> 1, wn = w & 1;
    int r = lane & 15, kq = lane >> 4;
    int bm = blockIdx.x * 128, bn = blockIdx.y * 128;

    f32x4 acc[4][4] = {};

    auto stage = [&](int buf, int k0) {
#pragma unroll
        for (int i = 0; i < 2; ++i) {
            int chunk = i * 256 + tid;           // 16B chunk id = row*4 + dest granule
            int row = chunk >> 2;
            int gs = (chunk & 3) ^ ((row >> 1) & 3);   // swizzled source granule
            const bf16* ga = A + (size_t)(bm + row) * K + k0 + gs * 8;
            gload16(ga, &ldsA[buf][(i * 256 + w * 64) * 8]);
            int brow = bn + row;
            if (FLAGS & GF_CLAMP) brow = min(brow, N - 1);
            const bf16* gb = Bt + (size_t)brow * K + k0 + gs * 8;
            gload16(gb, &ldsB[buf][(i * 256 + w * 64) * 8]);
        }
    };
    auto compute = [&](int buf) {
        bf16x8 af[4], bfr[4];
#pragma unroll
        for (int m = 0; m < 4; ++m) {
            int row = wm * 64 + m * 16 + r;
            af[m] = *reinterpret_cast<bf16x8*>(&ldsA[buf][row * 32 + (kq ^ ((row >> 1) & 3)) * 8]);
        }
#pragma unroll
        for (int n = 0; n < 4; ++n) {
            int row = wn * 64 + n * 16 + r;
            bfr[n] = *reinterpret_cast<bf16x8*>(&ldsB[buf][row * 32 + (kq ^ ((row >> 1) & 3)) * 8]);
        }
#pragma unroll
        for (int m = 0; m < 4; ++m)
#pragma unroll
            for (int n = 0; n < 4; ++n)
                acc[m][n] = MFMA16(af[m], bfr[n], acc[m][n]);
    };

    stage(0, 0);
    __syncthreads();
    int buf = 0;
    for (int k0 = 32; k0 < K; k0 += 32) {
        stage(buf ^ 1, k0);
        compute(buf);
        __syncthreads();
        buf ^= 1;
    }
    compute(buf);

    int row0 = bm + wm * 64, col0 = bn + wn * 64;
#pragma unroll
    for (int m = 0; m < 4; ++m) {
#pragma unroll
        for (int n = 0; n < 4; ++n) {
            int col = col0 + n * 16 + r;
            if (col < N) {
#pragma unroll
                for (int rr = 0; rr < 4; ++rr) {
                    int row = row0 + m * 16 + kq * 4 + rr;
                    float v = acc[m][n][rr];
                    if (bias) v += bias[col];
                    if (FLAGS & GF_GELU) v = gelu_tanh(v);
                    if (resid) v += resid[(size_t)row * N + col];
                    if (FLAGS & GF_OBF16) ((bf16*)C)[(size_t)row * N + col] = (bf16)v;
                    else                  ((float*)C)[(size_t)row * N + col] = v;
                }
            }
        }
    }
}

// ---------------- 256x256 8-phase GEMM (lm_head, round-8 best variant) ----------------
template<int FLAGS, int TAG>
__global__ __launch_bounds__(512, 1) void gemm256_8p(
    const bf16* __restrict__ A, const bf16* __restrict__ Bt,
    const float* __restrict__ bias, const float* __restrict__ resid,
    void* __restrict__ C, float2* __restrict__ partials,
    int M, int N, int K) {
    __shared__ short lds[2][2][256 * 64];        // [buf][A=0/B=1][row*64 + granule*8]
    int tid = threadIdx.x;                       // 0..511
    int lane = tid & 63, w = tid >> 6;
    int wm = w >> 2, wn = w & 3;                 // 2 x 4 waves
    int r = lane & 15, kq = lane >> 4;
    int bm = blockIdx.x * 256, bn = blockIdx.y * 256;

    f32x4 acc[8][4] = {};

    auto stage_half = [&](int buf, int kt, int half) {
        int mat = half >> 1;
        int hrow = (half & 1) * 128;
        const bf16* src = mat ? Bt : A;
        int base = mat ? bn : bm;
#pragma unroll
        for (int i = 0; i < 2; ++i) {
            int chunk = i * 512 + tid;               // 0..1023 = lrow*8 + dest granule
            int lrow = hrow + (chunk >> 3);
            int gsrc = (chunk & 7) ^ (lrow & 7);     // inverse-swizzled source granule
            int grow = base + lrow;
            if (mat && (FLAGS & GF_CLAMP)) grow = min(grow, N - 1);
            gload16(src + (size_t)grow * K + kt * 64 + gsrc * 8,
                    &lds[buf][mat][hrow * 64 + chunk * 8]);
        }
    };

    auto do_phase = [&](int buf, int p) {
        int mh = p >> 1, nh = p & 1;
        bf16x8 bfr[2][2], af[4][2];
#pragma unroll
        for (int n2 = 0; n2 < 2; ++n2) {
            int row = wn * 64 + (nh * 2 + n2) * 16 + r;
#pragma unroll
            for (int kk = 0; kk < 2; ++kk)
                bfr[n2][kk] = *reinterpret_cast<bf16x8*>(
                    &lds[buf][1][row * 64 + ((kk * 4 + kq) ^ (row & 7)) * 8]);
        }
#pragma unroll
        for (int m2 = 0; m2 < 4; ++m2) {
            int row = wm * 128 + (mh * 4 + m2) * 16 + r;
#pragma unroll
            for (int kk = 0; kk < 2; ++kk)
                af[m2][kk] = *reinterpret_cast<bf16x8*>(
                    &lds[buf][0][row * 64 + ((kk * 4 + kq) ^ (row & 7)) * 8]);
        }
        __builtin_amdgcn_s_setprio(1);
#pragma unroll
        for (int m2 = 0; m2 < 4; ++m2)
#pragma unroll
            for (int n2 = 0; n2 < 2; ++n2)
#pragma unroll
                for (int kk = 0; kk < 2; ++kk)
                    acc[mh * 4 + m2][nh * 2 + n2] =
                        MFMA16(af[m2][kk], bfr[n2][kk], acc[mh * 4 + m2][nh * 2 + n2]);
        __builtin_amdgcn_s_setprio(0);
    };

    const int NT = K / 64;
    stage_half(0, 0, 0); stage_half(0, 0, 1); stage_half(0, 0, 2); stage_half(0, 0, 3);
    for (int t = 0; t < NT; ++t) {
        int buf = t & 1;
        bool more = (t + 1 < NT);
        if (more) { stage_half(buf ^ 1, t + 1, 0); stage_half(buf ^ 1, t + 1, 1); }
        if (more) asm volatile("s_waitcnt vmcnt(4)" ::: "memory");
        else      asm volatile("s_waitcnt vmcnt(0)" ::: "memory");
        wg_barrier();                        // tile t resident for ALL waves
        do_phase(buf, 0);
        wg_barrier();
        if (more) { stage_half(buf ^ 1, t + 1, 2); stage_half(buf ^ 1, t + 1, 3); }
        do_phase(buf, 1);
        wg_barrier();
        do_phase(buf, 2);
        wg_barrier();
        do_phase(buf, 3);
        wg_barrier();
    }

    int row0 = bm + wm * 128, col0 = bn + wn * 64;
#pragma unroll
    for (int m = 0; m < 8; ++m) {
#pragma unroll
        for (int n = 0; n < 4; ++n) {
            int col = col0 + n * 16 + r;
            if (col < N) {
#pragma unroll
                for (int rr = 0; rr < 4; ++rr) {
                    int row = row0 + m * 16 + kq * 4 + rr;
                    float v = acc[m][n][rr];
                    if (bias) v += bias[col];
                    if (FLAGS & GF_GELU) v = gelu_tanh(v);
                    if (resid) v += resid[(size_t)row * N + col];
                    if (FLAGS & GF_OBF16) ((bf16*)C)[(size_t)row * N + col] = (bf16)v;
                    else                  ((float*)C)[(size_t)row * N + col] = v;
                }
            }
        }
    }

    if (FLAGS & GF_PARTIAL) {
        int chunk = (bn >> 6) + wn;              // 64-col chunk index
        if (chunk < NCHUNK) {
#pragma unroll
            for (int m = 0; m < 8; ++m) {
#pragma unroll
                for (int rr = 0; rr < 4; ++rr) {
                    float vals[4], mx = -INFINITY;
#pragma unroll
                    for (int n = 0; n < 4; ++n) {
                        int col = col0 + n * 16 + r;
                        float v = (col < N) ? acc[m][n][rr] : -INFINITY;
                        vals[n] = v;
                        mx = fmaxf(mx, v);
                    }
#pragma unroll
                    for (int o = 1; o < 16; o <<= 1) mx = fmaxf(mx, __shfl_xor(mx, o));
                    float sum = 0.f;
#pragma unroll
                    for (int n = 0; n < 4; ++n)
                        if (vals[n] > -INFINITY) sum += __expf(vals[n] - mx);
#pragma unroll
                    for (int o = 1; o < 16; o <<= 1) sum += __shfl_xor(sum, o);
                    if (r == 0) {
                        int row = row0 + m * 16 + kq * 4 + rr;
                        partials[(size_t)row * NCHUNK + chunk] = make_float2(mx, sum);
                    }
                }
            }
        }
    }
}

// ---------------- flash attention (T14 async reg-staged K/V, single LDS buffers) ----------------
// QBLK=64 (4 waves x 16 q-rows), KVBLK=128. Per tile: barrier -> write regs->LDS
// (global loads issued a full tile earlier, latency hidden under compute) ->
// barrier -> issue loads(t+1) -> QK^T/softmax/PV. LDS 49 KB keeps 3 blocks/CU.
__global__ __launch_bounds__(256) void flash_attn_kernel(const bf16* __restrict__ qkv,
                                                         bf16* __restrict__ ctx) {
    __shared__ short Ks[128 * 64];       // K tile [kv][64 d], granule ^= kv&7
    __shared__ short Vt[64 * 128];       // V^T tile [d][128 kv], granule ^= d&7
    __shared__ short Ps[4][16][132];     // per-wave P tile [qrow][kv], padded stride

    int tid = threadIdx.x, lane = tid & 63, w = tid >> 6;
    int r = lane & 15, kq = lane >> 4;
    int q0 = blockIdx.x * 64;
    int bh = blockIdx.y;
    int b = bh / NHEADS, h = bh % NHEADS;
    const int RS = 3 * DM;               // qkv row stride

    const bf16* qbase = qkv + (size_t)(b * TSEQ + q0 + w * 16 + r) * RS + h * 64;
    bf16x8 qf[2];
    qf[0] = *reinterpret_cast<const bf16x8*>(qbase + kq * 8);
    qf[1] = *reinterpret_cast<const bf16x8*>(qbase + 32 + kq * 8);

    f32x4 of[4] = {};
    float mrow[4] = {-INFINITY, -INFINITY, -INFINITY, -INFINITY};
    float lrow[4] = {};

    // staging: thread covers kv rows kvq*4..+3, d cols d0..d0+7
    int kvq = tid >> 3;                  // 0..31
    int d0 = (tid & 7) * 8;
    const bf16* kbase0 = qkv + (size_t)(b * TSEQ) * RS + DM + h * 64;
    const bf16* vbase0 = qkv + (size_t)(b * TSEQ) * RS + 2 * DM + h * 64;
    bf16x8 kr0, kr1, kr2, kr3, vr0, vr1, vr2, vr3;

    auto loadKV = [&](int t) {
        const bf16* kb = kbase0 + (size_t)(t * 128 + kvq * 4) * RS + d0;
        const bf16* vb = vbase0 + (size_t)(t * 128 + kvq * 4) * RS + d0;
        kr0 = *reinterpret_cast<const bf16x8*>(kb);
        kr1 = *reinterpret_cast<const bf16x8*>(kb + RS);
        kr2 = *reinterpret_cast<const bf16x8*>(kb + 2 * RS);
        kr3 = *reinterpret_cast<const bf16x8*>(kb + 3 * RS);
        vr0 = *reinterpret_cast<const bf16x8*>(vb);
        vr1 = *reinterpret_cast<const bf16x8*>(vb + RS);
        vr2 = *reinterpret_cast<const bf16x8*>(vb + 2 * RS);
        vr3 = *reinterpret_cast<const bf16x8*>(vb + 3 * RS);
    };
    auto writeKV = [&]() {
        // K: one b128 write per row, granule (tid&7) ^ (kv&7)
        bf16x8 krs[4] = {kr0, kr1, kr2, kr3};
#pragma unroll
        for (int j = 0; j < 4; ++j) {
            int kv = kvq * 4 + j;
            int pg = (tid & 7) ^ (kv & 7);
            *reinterpret_cast<bf16x8*>(&Ks[kv * 64 + pg * 8]) = krs[j];
        }
        // V^T: 8 packed b64 writes, kv-granule lg=kvq>>1 (4-bit), phys = lg ^ (d&7)
        int lg = kvq >> 1, half = kvq & 1;
#pragma unroll
        for (int jj = 0; jj < 8; ++jj) {
            int d = d0 + jj;
            int phys = lg ^ (d & 7);
            s16x4 pk = {vr0[jj], vr1[jj], vr2[jj], vr3[jj]};
            *reinterpret_cast<s16x4*>(&Vt[d * 128 + phys * 8 + half * 4]) = pk;
        }
    };

    int ntiles = (blockIdx.x >> 1) + 1;
    loadKV(0);
    for (int t = 0; t < ntiles; ++t) {
        __syncthreads();                 // all waves done reading previous tile's LDS
        writeKV();                       // regs landed long ago (compiler waitcnt)
        __syncthreads();                 // publish Ks/Vt
        if (t + 1 < ntiles) loadKV(t + 1);   // issue early; lands under compute

        int kv0 = t * 128;
        // ---- QK^T: 16 MFMA ----
        f32x4 sf[8];
#pragma unroll
        for (int n = 0; n < 8; ++n) sf[n] = (f32x4){0.f, 0.f, 0.f, 0.f};
        __builtin_amdgcn_s_setprio(1);
#pragma unroll
        for (int n = 0; n < 8; ++n) {
            int row = n * 16 + r;
#pragma unroll
            for (int kt = 0; kt < 2; ++kt) {
                int gran = (kt * 4 + kq) ^ (row & 7);
                bf16x8 kf = *reinterpret_cast<bf16x8*>(&Ks[row * 64 + gran * 8]);
                sf[n] = MFMA16(qf[kt], kf, sf[n]);
            }
        }
        __builtin_amdgcn_s_setprio(0);

        // ---- online softmax over 128 cols ----
        bool diag = (kv0 + 128 > q0);
        float alpha[4];
#pragma unroll
        for (int rr = 0; rr < 4; ++rr) {
            int qrow = q0 + w * 16 + kq * 4 + rr;
            float vals[8];
            float mx = mrow[rr];
#pragma unroll
            for (int n = 0; n < 8; ++n) {
                float v = sf[n][rr] * 0.125f;
                if (diag && (kv0 + n * 16 + r) > qrow) v = -INFINITY;
                vals[n] = v;
                mx = fmaxf(mx, v);
            }
#pragma unroll
            for (int o = 1; o < 16; o <<= 1) mx = fmaxf(mx, __shfl_xor(mx, o));
            float al = __expf(mrow[rr] - mx);
            float sum = 0.f;
#pragma unroll
            for (int n = 0; n < 8; ++n) {
                float p = __expf(vals[n] - mx);
                vals[n] = p;
                sum += p;
            }
#pragma unroll
            for (int o = 1; o < 16; o <<= 1) sum += __shfl_xor(sum, o);
            mrow[rr] = mx;
            lrow[rr] = lrow[rr] * al + sum;
            alpha[rr] = al;
#pragma unroll
            for (int n = 0; n < 8; ++n) Ps[w][kq * 4 + rr][n * 16 + r] = f2bf(vals[n]);
        }
#pragma unroll
        for (int n = 0; n < 4; ++n)
#pragma unroll
            for (int rr = 0; rr < 4; ++rr) of[n][rr] *= alpha[rr];

        // ---- PV: 16 MFMA, V^T frags via swizzled reads ----
        __builtin_amdgcn_s_setprio(1);
#pragma unroll
        for (int kt = 0; kt < 4; ++kt) {
            bf16x8 pa = *reinterpret_cast<bf16x8*>(&Ps[w][r][kt * 32 + kq * 8]);
#pragma unroll
            for (int n = 0; n < 4; ++n) {
                int row = n * 16 + r;
                int gran = (kt * 4 + kq) ^ (row & 7);
                bf16x8 vf = *reinterpret_cast<bf16x8*>(&Vt[row * 128 + gran * 8]);
                of[n] = MFMA16(pa, vf, of[n]);
            }
        }
        __builtin_amdgcn_s_setprio(0);
    }

    // ---- epilogue ----
#pragma unroll
    for (int rr = 0; rr < 4; ++rr) {
        float inv = 1.0f / lrow[rr];
        int qrow = q0 + w * 16 + kq * 4 + rr;
        bf16* cb = ctx + (size_t)(b * TSEQ + qrow) * DM + h * 64;
#pragma unroll
        for (int n = 0; n < 4; ++n) cb[n * 16 + r] = (bf16)(of[n][rr] * inv);
    }
}

// ---------------- loss: merge per-chunk partials ----------------
__global__ __launch_bounds__(256) void loss_reduce_kernel(const float2* __restrict__ partials,
                                                          const float* __restrict__ logits,
                                                          const int* __restrict__ target,
                                                          float* __restrict__ nll) {
    int row = blockIdx.x, tid = threadIdx.x;
    const float2* pr = partials + (size_t)row * NCHUNK;
    float m = -INFINITY, s = 0.f;
    for (int c = tid; c < NCHUNK; c += 256) {
        float2 p = pr[c];
        if (p.x > m) { s = s * __expf(m - p.x) + p.y; m = p.x; }
        else         { s += p.y * __expf(p.x - m); }
    }
    __shared__ float sm[256], ssum[256];
    sm[tid] = m; ssum[tid] = s; __syncthreads();
    for (int o = 128; o; o >>= 1) {
        if (tid < o) {
            float m2 = sm[tid + o], s2 = ssum[tid + o];
            float mm = fmaxf(sm[tid], m2);
            ssum[tid] = ssum[tid] * __expf(sm[tid] - mm) + s2 * __expf(m2 - mm);
            sm[tid] = mm;
        }
        __syncthreads();
    }
    if (tid == 0) {
        float lse = sm[0] + logf(ssum[0]);
        nll[row] = lse - logits[(size_t)row * VOCAB + target[row]];
    }
}

__global__ void loss2_kernel(const float* __restrict__ nll, float* __restrict__ loss) {
    int tid = threadIdx.x;
    float s = 0.f;
    for (int i = tid; i < BT; i += 1024) s += nll[i];
    __shared__ float r[1024];
    r[tid] = s; __syncthreads();
    for (int o = 512; o; o >>= 1) { if (tid < o) r[tid] += r[tid + o]; __syncthreads(); }
    if (tid == 0) *loss = r[0] * (1.0f / BT);
}

// ---------------- launcher ----------------
extern "C" void kernel_launch(void* const* d_in, const int* in_sizes, int n_in,
                              void* d_out, int out_size, void* d_ws, size_t ws_size,
                              hipStream_t stream) {
    const int*   inp    = (const int*)  d_in[0];
    const int*   target = (const int*)  d_in[1];
    const float* wte    = (const float*)d_in[2];
    const float* wpe    = (const float*)d_in[3];
    const float* ln1_w  = (const float*)d_in[4];
    const float* ln1_b  = (const float*)d_in[5];
    const float* attn_w = (const float*)d_in[6];
    const float* attn_b = (const float*)d_in[7];
    const float* proj_w = (const float*)d_in[8];
    const float* proj_b = (const float*)d_in[9];
    const float* ln2_w  = (const float*)d_in[10];
    const float* ln2_b  = (const float*)d_in[11];
    const float* fc_w   = (const float*)d_in[12];
    const float* fc_b   = (const float*)d_in[13];
    const float* fc2_w  = (const float*)d_in[14];
    const float* fc2_b  = (const float*)d_in[15];
    const float* lnf_w  = (const float*)d_in[16];
    const float* lnf_b  = (const float*)d_in[17];
    float* out = (float*)d_out;

    char* p = (char*)d_ws;
    auto alloc = [&](size_t bytes) { char* q = p; p += (bytes + 255) & ~(size_t)255; return q; };
    float* x     = (float*)alloc((size_t)BT * DM * 4);
    float* nll   = (float*)alloc((size_t)BT * 4);
    bf16*  qkvb  = (bf16*) alloc((size_t)BT * 3 * DM * 2);
    bf16*  tmpb  = (bf16*) alloc((size_t)BT * DM * 2);
    bf16*  ctxb  = (bf16*) alloc((size_t)BT * DM * 2);
    bf16*  hb    = (bf16*) alloc((size_t)BT * 4 * DM * 2);
    bf16*  wteb  = (bf16*) alloc((size_t)VOCAB * DM * 2);
    bf16*  wqkvT = (bf16*) alloc((size_t)NLAYERS * 3 * DM * DM * 2);
    bf16*  wprojT= (bf16*) alloc((size_t)NLAYERS * DM * DM * 2);
    bf16*  wfcT  = (bf16*) alloc((size_t)NLAYERS * 4 * DM * DM * 2);
    bf16*  wfc2T = (bf16*) alloc((size_t)NLAYERS * 4 * DM * DM * 2);
    // loss partials (25.8 MB) alias the ctxb+hb region (31.5 MB, dead after layer loop)
    float2* partials = (float2*)ctxb;

    dim3 tb(32, 8);
    transpose_bf16_kernel<<<dim3(3 * DM / 32, DM / 32, NLAYERS), tb, 0, stream>>>(attn_w, wqkvT, DM, 3 * DM);
    transpose_bf16_kernel<<<dim3(DM / 32, DM / 32, NLAYERS), tb, 0, stream>>>(proj_w, wprojT, DM, DM);
    transpose_bf16_kernel<<<dim3(4 * DM / 32, DM / 32, NLAYERS), tb, 0, stream>>>(fc_w, wfcT, DM, 4 * DM);
    transpose_bf16_kernel<<<dim3(DM / 32, 4 * DM / 32, NLAYERS), tb, 0, stream>>>(fc2_w, wfc2T, 4 * DM, DM);
    {
        size_t n = (size_t)VOCAB * DM;
        tobf16_kernel<<<(unsigned)((n + 255) / 256), 256, 0, stream>>>(wte, wteb, n);
    }

    embed_kernel<<<BT * DM / 4 / 256, 256, 0, stream>>>(inp, wte, wpe, x);

    for (int i = 0; i < NLAYERS; ++i) {
        ln_kernel<<<BT / 4, 256, 0, stream>>>(x, ln1_w + i * DM, ln1_b + i * DM, tmpb);
        gemm_k<GF_OBF16, 0><<<dim3(BT / 128, 3 * DM / 128), 256, 0, stream>>>(
            tmpb, wqkvT + (size_t)i * 3 * DM * DM, attn_b + i * 3 * DM, nullptr,
            qkvb, nullptr, BT, 3 * DM, DM);
        flash_attn_kernel<<<dim3(TSEQ / 64, 4 * NHEADS), 256, 0, stream>>>(qkvb, ctxb);
        gemm_k<0, 1><<<dim3(BT / 128, DM / 128), 256, 0, stream>>>(
            ctxb, wprojT + (size_t)i * DM * DM, proj_b + i * DM, x,
            x, nullptr, BT, DM, DM);
        ln_kernel<<<BT / 4, 256, 0, stream>>>(x, ln2_w + i * DM, ln2_b + i * DM, tmpb);
        gemm_k<GF_GELU | GF_OBF16, 2><<<dim3(BT / 128, 4 * DM / 128), 256, 0, stream>>>(
            tmpb, wfcT + (size_t)i * 4 * DM * DM, fc_b + i * 4 * DM, nullptr,
            hb, nullptr, BT, 4 * DM, DM);
        gemm_k<0, 3><<<dim3(BT / 128, DM / 128), 256, 0, stream>>>(
            hb, wfc2T + (size_t)i * 4 * DM * DM, fc2_b + i * DM, x,
            x, nullptr, BT, DM, 4 * DM);
    }

    ln_kernel<<<BT / 4, 256, 0, stream>>>(x, lnf_w, lnf_b, tmpb);
    gemm256_8p<GF_CLAMP | GF_PARTIAL, 4><<<dim3(BT / 256, (VOCAB + 255) / 256), 512, 0, stream>>>(
        tmpb, wteb, nullptr, nullptr, out, partials, BT, VOCAB, DM);
    loss_reduce_kernel<<<BT, 256, 0, stream>>>(partials, out, target, nll);
    loss2_kernel<<<1, 1024, 0, stream>>>(nll, out + (size_t)out_size - 1);
}

// Round 11
// 4241.860 us; speedup vs baseline: 1.0233x; 1.0047x over previous
//
#include <hip/hip_runtime.h>
#include <hip/hip_bf16.h>
#include <cmath>

#define NLAYERS 12
#define NHEADS  12
#define DM      768
#define VOCAB   50257
#define TSEQ    1024
#define BT      4096   // B*T
#define NCHUNK  786    // ceil(VOCAB/64) col-chunks for loss partials

typedef __attribute__((ext_vector_type(4))) float f32x4;
typedef __attribute__((ext_vector_type(8))) short bf16x8;
typedef __attribute__((ext_vector_type(4))) short s16x4;

typedef __hip_bfloat16 bf16;

#define MFMA16(a, b, c) __builtin_amdgcn_mfma_f32_16x16x32_bf16(a, b, c, 0, 0, 0)

// ---------------- helpers ----------------
__device__ __forceinline__ void gload16(const void* g, void* l) {
    __builtin_amdgcn_global_load_lds(
        (const __attribute__((address_space(1))) void*)g,
        (__attribute__((address_space(3))) void*)l, 16, 0, 0);
}

// raw s_barrier with compiler memory fences (no forced vmcnt(0) drain)
__device__ __forceinline__ void wg_barrier() {
    asm volatile("" ::: "memory");
    __builtin_amdgcn_s_barrier();
    asm volatile("" ::: "memory");
}

__device__ __forceinline__ float gelu_tanh(float v) {
    float u = 0.7978845608028654f * (v + 0.044715f * v * v * v);
    return 0.5f * v * (1.0f + tanhf(u));
}

__device__ __forceinline__ short f2bf(float f) {
    bf16 h = (bf16)f;
    return *reinterpret_cast<short*>(&h);
}

struct ushort4s { short a, b, c, d; };

// ---------------- weight prep ----------------
__global__ void transpose_bf16_kernel(const float* __restrict__ in, bf16* __restrict__ out,
                                      int K, int N) {
    __shared__ float tile[32][33];
    size_t lofs = (size_t)blockIdx.z * K * N;
    int k0 = blockIdx.y * 32, n0 = blockIdx.x * 32;
    int tx = threadIdx.x, ty = threadIdx.y;      // 32x8
#pragma unroll
    for (int i = 0; i < 32; i += 8)
        tile[ty + i][tx] = in[lofs + (size_t)(k0 + ty + i) * N + n0 + tx];
    __syncthreads();
#pragma unroll
    for (int i = 0; i < 32; i += 8)
        out[lofs + (size_t)(n0 + ty + i) * K + k0 + tx] = (bf16)tile[tx][ty + i];
}

__global__ void tobf16_kernel(const float* __restrict__ in, bf16* __restrict__ out, size_t n) {
    size_t i = (size_t)blockIdx.x * 256 + threadIdx.x;
    if (i < n) out[i] = (bf16)in[i];
}

// ---------------- embedding (fp32 residual stream, float4) ----------------
__global__ void embed_kernel(const int* __restrict__ inp, const float* __restrict__ wte,
                             const float* __restrict__ wpe, float* __restrict__ x) {
    int idx = blockIdx.x * 256 + threadIdx.x;    // over BT*DM/4
    int m = idx / (DM / 4), c4 = idx % (DM / 4);
    int tok = inp[m];
    int t = m & (TSEQ - 1);
    float4 a = reinterpret_cast<const float4*>(wte)[(size_t)tok * (DM / 4) + c4];
    float4 b = reinterpret_cast<const float4*>(wpe)[(size_t)t * (DM / 4) + c4];
    float4 o = {a.x + b.x, a.y + b.y, a.z + b.z, a.w + b.w};
    reinterpret_cast<float4*>(x)[idx] = o;
}

// ---------------- layernorm: one row per WAVE (no block sync) ----------------
__global__ __launch_bounds__(256) void ln_kernel(const float* __restrict__ x,
                                                 const float* __restrict__ w,
                                                 const float* __restrict__ b,
                                                 bf16* __restrict__ y) {
    int tid = threadIdx.x, wv = tid >> 6, lane = tid & 63;
    int row = blockIdx.x * 4 + wv;
    const float4* xr = reinterpret_cast<const float4*>(x + (size_t)row * DM);
    float4 v[3];
    float s = 0.f, q = 0.f;
#pragma unroll
    for (int j = 0; j < 3; ++j) {
        v[j] = xr[lane + 64 * j];
        s += v[j].x + v[j].y + v[j].z + v[j].w;
        q += v[j].x * v[j].x + v[j].y * v[j].y + v[j].z * v[j].z + v[j].w * v[j].w;
    }
#pragma unroll
    for (int o = 1; o < 64; o <<= 1) { s += __shfl_xor(s, o); q += __shfl_xor(q, o); }
    float mu  = s * (1.0f / DM);
    float var = q * (1.0f / DM) - mu * mu;
    float inv = rsqrtf(var + 1e-5f);
#pragma unroll
    for (int j = 0; j < 3; ++j) {
        int c4 = lane + 64 * j;
        float4 wv4 = reinterpret_cast<const float4*>(w)[c4];
        float4 bv4 = reinterpret_cast<const float4*>(b)[c4];
        ushort4s o;
        o.a = f2bf((v[j].x - mu) * inv * wv4.x + bv4.x);
        o.b = f2bf((v[j].y - mu) * inv * wv4.y + bv4.y);
        o.c = f2bf((v[j].z - mu) * inv * wv4.z + bv4.z);
        o.d = f2bf((v[j].w - mu) * inv * wv4.w + bv4.w);
        *reinterpret_cast<ushort4s*>(y + (size_t)row * DM + c4 * 4) = o;
    }
}

#define GF_GELU    1
#define GF_OBF16   2
#define GF_CLAMP   4
#define GF_PARTIAL 8

// ---------------- 128x128 2-phase GEMM (qkv / proj / fc / fc2) ----------------
template<int FLAGS, int TAG>
__global__ __launch_bounds__(256) void gemm_k(
    const bf16* __restrict__ A, const bf16* __restrict__ Bt,
    const float* __restrict__ bias, const float* __restrict__ resid,
    void* __restrict__ C, float2* __restrict__ partials,
    int M, int N, int K) {
    __shared__ short ldsA[2][128 * 32];
    __shared__ short ldsB[2][128 * 32];
    int tid = threadIdx.x;
    int lane = tid & 63, w = tid >> 6;
    int wm = w >> 1, wn = w & 1;
    int r = lane & 15, kq = lane >> 4;
    int bm = blockIdx.x * 128, bn = blockIdx.y * 128;

    f32x4 acc[4][4] = {};

    auto stage = [&](int buf, int k0) {
#pragma unroll
        for (int i = 0; i < 2; ++i) {
            int chunk = i * 256 + tid;           // 16B chunk id = row*4 + dest granule
            int row = chunk >> 2;
            int gs = (chunk & 3) ^ ((row >> 1) & 3);   // swizzled source granule
            const bf16* ga = A + (size_t)(bm + row) * K + k0 + gs * 8;
            gload16(ga, &ldsA[buf][(i * 256 + w * 64) * 8]);
            int brow = bn + row;
            const bf16* gb = Bt + (size_t)brow * K + k0 + gs * 8;
            gload16(gb, &ldsB[buf][(i * 256 + w * 64) * 8]);
        }
    };
    auto compute = [&](int buf) {
        bf16x8 af[4], bfr[4];
#pragma unroll
        for (int m = 0; m < 4; ++m) {
            int row = wm * 64 + m * 16 + r;
            af[m] = *reinterpret_cast<bf16x8*>(&ldsA[buf][row * 32 + (kq ^ ((row >> 1) & 3)) * 8]);
        }
#pragma unroll
        for (int n = 0; n < 4; ++n) {
            int row = wn * 64 + n * 16 + r;
            bfr[n] = *reinterpret_cast<bf16x8*>(&ldsB[buf][row * 32 + (kq ^ ((row >> 1) & 3)) * 8]);
        }
#pragma unroll
        for (int m = 0; m < 4; ++m)
#pragma unroll
            for (int n = 0; n < 4; ++n)
                acc[m][n] = MFMA16(af[m], bfr[n], acc[m][n]);
    };

    stage(0, 0);
    __syncthreads();
    int buf = 0;
    for (int k0 = 32; k0 < K; k0 += 32) {
        stage(buf ^ 1, k0);
        compute(buf);
        __syncthreads();
        buf ^= 1;
    }
    compute(buf);

    int row0 = bm + wm * 64, col0 = bn + wn * 64;
#pragma unroll
    for (int m = 0; m < 4; ++m) {
#pragma unroll
        for (int n = 0; n < 4; ++n) {
            int col = col0 + n * 16 + r;
#pragma unroll
            for (int rr = 0; rr < 4; ++rr) {
                int row = row0 + m * 16 + kq * 4 + rr;
                float v = acc[m][n][rr];
                if (bias) v += bias[col];
                if (FLAGS & GF_GELU) v = gelu_tanh(v);
                if (resid) v += resid[(size_t)row * N + col];
                if (FLAGS & GF_OBF16) ((bf16*)C)[(size_t)row * N + col] = (bf16)v;
                else                  ((float*)C)[(size_t)row * N + col] = v;
            }
        }
    }
}

// ---------------- 128x256 GEMM, 8 waves x 64x64 (lm_head) ----------------
// BK=32, dbuf LDS 48 KB, counted vmcnt(3), raw barriers. Per-wave acc = 64 VGPR
// -> __launch_bounds__(512,4) holds 4 waves/SIMD (2 blocks/CU), 2x r8 occupancy.
template<int FLAGS, int TAG>
__global__ __launch_bounds__(512, 4) void gemm_wide(
    const bf16* __restrict__ A, const bf16* __restrict__ Bt,
    const float* __restrict__ bias, const float* __restrict__ resid,
    void* __restrict__ C, float2* __restrict__ partials,
    int M, int N, int K) {
    __shared__ short ldsA[2][128 * 32];          // 2 x 8 KB
    __shared__ short ldsB[2][256 * 32];          // 2 x 16 KB
    int tid = threadIdx.x;                       // 0..511
    int lane = tid & 63, w = tid >> 6;
    int wm = w >> 2, wn = w & 3;                 // 2M x 4N waves, 64x64 each
    int r = lane & 15, kq = lane >> 4;
    int bm = blockIdx.x * 128, bn = blockIdx.y * 256;

    f32x4 acc[4][4] = {};

    auto stage = [&](int buf, int kt) {
        int k0 = kt * 32;
        {   // A tile: 512 chunks, 1 per thread
            int row = tid >> 2;
            int gs = (tid & 3) ^ ((row >> 1) & 3);
            gload16(A + (size_t)(bm + row) * K + k0 + gs * 8, &ldsA[buf][tid * 8]);
        }
#pragma unroll
        for (int i = 0; i < 2; ++i) {            // B tile: 1024 chunks, 2 per thread
            int chunk = i * 512 + tid;
            int row = chunk >> 2;
            int gs = (chunk & 3) ^ ((row >> 1) & 3);
            int grow = bn + row;
            if (FLAGS & GF_CLAMP) grow = min(grow, N - 1);
            gload16(Bt + (size_t)grow * K + k0 + gs * 8, &ldsB[buf][chunk * 8]);
        }
    };
    auto compute = [&](int buf) {
        bf16x8 af[4], bfr[4];
#pragma unroll
        for (int m = 0; m < 4; ++m) {
            int row = wm * 64 + m * 16 + r;
            af[m] = *reinterpret_cast<bf16x8*>(&ldsA[buf][row * 32 + (kq ^ ((row >> 1) & 3)) * 8]);
        }
#pragma unroll
        for (int n = 0; n < 4; ++n) {
            int row = wn * 64 + n * 16 + r;
            bfr[n] = *reinterpret_cast<bf16x8*>(&ldsB[buf][row * 32 + (kq ^ ((row >> 1) & 3)) * 8]);
        }
        __builtin_amdgcn_s_setprio(1);
#pragma unroll
        for (int m = 0; m < 4; ++m)
#pragma unroll
            for (int n = 0; n < 4; ++n)
                acc[m][n] = MFMA16(af[m], bfr[n], acc[m][n]);
        __builtin_amdgcn_s_setprio(0);
    };

    const int NT = K / 32;                       // 24
    stage(0, 0);
    asm volatile("s_waitcnt vmcnt(0)" ::: "memory");
    wg_barrier();
    for (int t = 0; t < NT; ++t) {
        int buf = t & 1;
        bool more = (t + 1 < NT);
        if (more) {
            stage(buf ^ 1, t + 1);               // 3 loads fly across barriers
            asm volatile("s_waitcnt vmcnt(3)" ::: "memory");   // tile t fully landed
        } else {
            asm volatile("s_waitcnt vmcnt(0)" ::: "memory");
        }
        wg_barrier();                            // tile t resident for ALL waves
        compute(buf);
        wg_barrier();                            // all reads done before t+2 lands here
    }

    int row0 = bm + wm * 64, col0 = bn + wn * 64;
#pragma unroll
    for (int m = 0; m < 4; ++m) {
#pragma unroll
        for (int n = 0; n < 4; ++n) {
            int col = col0 + n * 16 + r;
            if (col < N) {
#pragma unroll
                for (int rr = 0; rr < 4; ++rr) {
                    int row = row0 + m * 16 + kq * 4 + rr;
                    float v = acc[m][n][rr];
                    if (bias) v += bias[col];
                    if (FLAGS & GF_GELU) v = gelu_tanh(v);
                    if (resid) v += resid[(size_t)row * N + col];
                    if (FLAGS & GF_OBF16) ((bf16*)C)[(size_t)row * N + col] = (bf16)v;
                    else                  ((float*)C)[(size_t)row * N + col] = v;
                }
            }
        }
    }

    if (FLAGS & GF_PARTIAL) {
        int chunk = (bn >> 6) + wn;              // 64-col chunk index
        if (chunk < NCHUNK) {
#pragma unroll
            for (int m = 0; m < 4; ++m) {
#pragma unroll
                for (int rr = 0; rr < 4; ++rr) {
                    float vals[4], mx = -INFINITY;
#pragma unroll
                    for (int n = 0; n < 4; ++n) {
                        int col = col0 + n * 16 + r;
                        float v = (col < N) ? acc[m][n][rr] : -INFINITY;
                        vals[n] = v;
                        mx = fmaxf(mx, v);
                    }
#pragma unroll
                    for (int o = 1; o < 16; o <<= 1) mx = fmaxf(mx, __shfl_xor(mx, o));
                    float sum = 0.f;
#pragma unroll
                    for (int n = 0; n < 4; ++n)
                        if (vals[n] > -INFINITY) sum += __expf(vals[n] - mx);
#pragma unroll
                    for (int o = 1; o < 16; o <<= 1) sum += __shfl_xor(sum, o);
                    if (r == 0) {
                        int row = row0 + m * 16 + kq * 4 + rr;
                        partials[(size_t)row * NCHUNK + chunk] = make_float2(mx, sum);
                    }
                }
            }
        }
    }
}

// ---------------- flash attention: QBLK=128, 8 waves, reg-staged K/V ----------------
// Waves 0-3 stage K, 4-7 stage V (16 VGPR each). K/V tile shared by 128 q-rows
// (2x reuse vs QBLK=64 -> staging + barrier overhead halves). Longest-first order.
__global__ __launch_bounds__(512, 4) void flash_attn_kernel(const bf16* __restrict__ qkv,
                                                            bf16* __restrict__ ctx) {
    __shared__ short Ks[128 * 64];       // K tile [kv][64 d], granule ^= kv&7
    __shared__ short Vt[64 * 128];       // V^T tile [d][128 kv], granule ^= d&7
    __shared__ short Ps[8][16][132];     // per-wave P tile [qrow][kv], padded

    int tid = threadIdx.x, lane = tid & 63, w = tid >> 6;   // 8 waves
    int r = lane & 15, kq = lane >> 4;
    int qt = (int)gridDim.x - 1 - (int)blockIdx.x;           // longest first
    int q0 = qt * 128;
    int bh = blockIdx.y;
    int b = bh / NHEADS, h = bh % NHEADS;
    const int RS = 3 * DM;

    const bf16* qbase = qkv + (size_t)(b * TSEQ + q0 + w * 16 + r) * RS + h * 64;
    bf16x8 qf[2];
    qf[0] = *reinterpret_cast<const bf16x8*>(qbase + kq * 8);
    qf[1] = *reinterpret_cast<const bf16x8*>(qbase + 32 + kq * 8);

    f32x4 of[4] = {};
    float mrow[4] = {-INFINITY, -INFINITY, -INFINITY, -INFINITY};
    float lrow[4] = {};

    // staging split: tid<256 stage K, tid>=256 stage V. Each: 4 kv rows x 8 d.
    int stid = tid & 255;
    int kvq = stid >> 3;                 // 0..31 -> kv rows kvq*4..+3
    int d0 = (stid & 7) * 8;
    bool isK = tid < 256;
    const bf16* sb0 = qkv + (size_t)(b * TSEQ) * RS + (isK ? DM : 2 * DM) + h * 64;
    bf16x8 r0, r1, r2, r3;

    auto loadKV = [&](int t) {
        const bf16* p = sb0 + (size_t)(t * 128 + kvq * 4) * RS + d0;
        r0 = *reinterpret_cast<const bf16x8*>(p);
        r1 = *reinterpret_cast<const bf16x8*>(p + RS);
        r2 = *reinterpret_cast<const bf16x8*>(p + 2 * RS);
        r3 = *reinterpret_cast<const bf16x8*>(p + 3 * RS);
    };
    auto writeKV = [&]() {
        if (isK) {
            bf16x8 rs[4] = {r0, r1, r2, r3};
#pragma unroll
            for (int j = 0; j < 4; ++j) {
                int kv = kvq * 4 + j;
                int pg = (stid & 7) ^ (kv & 7);
                *reinterpret_cast<bf16x8*>(&Ks[kv * 64 + pg * 8]) = rs[j];
            }
        } else {
            int lg = kvq >> 1, half = kvq & 1;
#pragma unroll
            for (int jj = 0; jj < 8; ++jj) {
                int d = d0 + jj;
                int phys = lg ^ (d & 7);
                s16x4 pk = {r0[jj], r1[jj], r2[jj], r3[jj]};
                *reinterpret_cast<s16x4*>(&Vt[d * 128 + phys * 8 + half * 4]) = pk;
            }
        }
    };

    int ntiles = qt + 1;
    loadKV(0);
    for (int t = 0; t < ntiles; ++t) {
        __syncthreads();                 // prior tile's LDS reads done
        writeKV();
        __syncthreads();                 // publish Ks/Vt
        if (t + 1 < ntiles) loadKV(t + 1);   // lands under this tile's compute

        int kv0 = t * 128;
        // ---- QK^T: 16 MFMA ----
        f32x4 sf[8];
#pragma unroll
        for (int n = 0; n < 8; ++n) sf[n] = (f32x4){0.f, 0.f, 0.f, 0.f};
        __builtin_amdgcn_s_setprio(1);
#pragma unroll
        for (int n = 0; n < 8; ++n) {
            int row = n * 16 + r;
#pragma unroll
            for (int kt = 0; kt < 2; ++kt) {
                int gran = (kt * 4 + kq) ^ (row & 7);
                bf16x8 kf = *reinterpret_cast<bf16x8*>(&Ks[row * 64 + gran * 8]);
                sf[n] = MFMA16(qf[kt], kf, sf[n]);
            }
        }
        __builtin_amdgcn_s_setprio(0);

        // ---- online softmax over 128 cols ----
        bool diag = (kv0 + 128 > q0);
        float alpha[4];
#pragma unroll
        for (int rr = 0; rr < 4; ++rr) {
            int qrow = q0 + w * 16 + kq * 4 + rr;
            float vals[8];
            float mx = mrow[rr];
#pragma unroll
            for (int n = 0; n < 8; ++n) {
                float v = sf[n][rr] * 0.125f;
                if (diag && (kv0 + n * 16 + r) > qrow) v = -INFINITY;
                vals[n] = v;
                mx = fmaxf(mx, v);
            }
#pragma unroll
            for (int o = 1; o < 16; o <<= 1) mx = fmaxf(mx, __shfl_xor(mx, o));
            float al = __expf(mrow[rr] - mx);
            float sum = 0.f;
#pragma unroll
            for (int n = 0; n < 8; ++n) {
                float p = __expf(vals[n] - mx);
                vals[n] = p;
                sum += p;
            }
#pragma unroll
            for (int o = 1; o < 16; o <<= 1) sum += __shfl_xor(sum, o);
            mrow[rr] = mx;
            lrow[rr] = lrow[rr] * al + sum;
            alpha[rr] = al;
#pragma unroll
            for (int n = 0; n < 8; ++n) Ps[w][kq * 4 + rr][n * 16 + r] = f2bf(vals[n]);
        }
#pragma unroll
        for (int n = 0; n < 4; ++n)
#pragma unroll
            for (int rr = 0; rr < 4; ++rr) of[n][rr] *= alpha[rr];

        // ---- PV: 16 MFMA ----
        __builtin_amdgcn_s_setprio(1);
#pragma unroll
        for (int kt = 0; kt < 4; ++kt) {
            bf16x8 pa = *reinterpret_cast<bf16x8*>(&Ps[w][r][kt * 32 + kq * 8]);
#pragma unroll
            for (int n = 0; n < 4; ++n) {
                int row = n * 16 + r;
                int gran = (kt * 4 + kq) ^ (row & 7);
                bf16x8 vf = *reinterpret_cast<bf16x8*>(&Vt[row * 128 + gran * 8]);
                of[n] = MFMA16(pa, vf, of[n]);
            }
        }
        __builtin_amdgcn_s_setprio(0);
    }

    // ---- epilogue ----
#pragma unroll
    for (int rr = 0; rr < 4; ++rr) {
        float inv = 1.0f / lrow[rr];
        int qrow = q0 + w * 16 + kq * 4 + rr;
        bf16* cb = ctx + (size_t)(b * TSEQ + qrow) * DM + h * 64;
#pragma unroll
        for (int n = 0; n < 4; ++n) cb[n * 16 + r] = (bf16)(of[n][rr] * inv);
    }
}

// ---------------- loss: merge per-chunk partials ----------------
__global__ __launch_bounds__(256) void loss_reduce_kernel(const float2* __restrict__ partials,
                                                          const float* __restrict__ logits,
                                                          const int* __restrict__ target,
                                                          float* __restrict__ nll) {
    int row = blockIdx.x, tid = threadIdx.x;
    const float2* pr = partials + (size_t)row * NCHUNK;
    float m = -INFINITY, s = 0.f;
    for (int c = tid; c < NCHUNK; c += 256) {
        float2 p = pr[c];
        if (p.x > m) { s = s * __expf(m - p.x) + p.y; m = p.x; }
        else         { s += p.y * __expf(p.x - m); }
    }
    __shared__ float sm[256], ssum[256];
    sm[tid] = m; ssum[tid] = s; __syncthreads();
    for (int o = 128; o; o >>= 1) {
        if (tid < o) {
            float m2 = sm[tid + o], s2 = ssum[tid + o];
            float mm = fmaxf(sm[tid], m2);
            ssum[tid] = ssum[tid] * __expf(sm[tid] - mm) + s2 * __expf(m2 - mm);
            sm[tid] = mm;
        }
        __syncthreads();
    }
    if (tid == 0) {
        float lse = sm[0] + logf(ssum[0]);
        nll[row] = lse - logits[(size_t)row * VOCAB + target[row]];
    }
}

__global__ void loss2_kernel(const float* __restrict__ nll, float* __restrict__ loss) {
    int tid = threadIdx.x;
    float s = 0.f;
    for (int i = tid; i < BT; i += 1024) s += nll[i];
    __shared__ float r[1024];
    r[tid] = s; __syncthreads();
    for (int o = 512; o; o >>= 1) { if (tid < o) r[tid] += r[tid + o]; __syncthreads(); }
    if (tid == 0) *loss = r[0] * (1.0f / BT);
}

// ---------------- launcher ----------------
extern "C" void kernel_launch(void* const* d_in, const int* in_sizes, int n_in,
                              void* d_out, int out_size, void* d_ws, size_t ws_size,
                              hipStream_t stream) {
    const int*   inp    = (const int*)  d_in[0];
    const int*   target = (const int*)  d_in[1];
    const float* wte    = (const float*)d_in[2];
    const float* wpe    = (const float*)d_in[3];
    const float* ln1_w  = (const float*)d_in[4];
    const float* ln1_b  = (const float*)d_in[5];
    const float* attn_w = (const float*)d_in[6];
    const float* attn_b = (const float*)d_in[7];
    const float* proj_w = (const float*)d_in[8];
    const float* proj_b = (const float*)d_in[9];
    const float* ln2_w  = (const float*)d_in[10];
    const float* ln2_b  = (const float*)d_in[11];
    const float* fc_w   = (const float*)d_in[12];
    const float* fc_b   = (const float*)d_in[13];
    const float* fc2_w  = (const float*)d_in[14];
    const float* fc2_b  = (const float*)d_in[15];
    const float* lnf_w  = (const float*)d_in[16];
    const float* lnf_b  = (const float*)d_in[17];
    float* out = (float*)d_out;

    char* p = (char*)d_ws;
    auto alloc = [&](size_t bytes) { char* q = p; p += (bytes + 255) & ~(size_t)255; return q; };
    float* x     = (float*)alloc((size_t)BT * DM * 4);
    float* nll   = (float*)alloc((size_t)BT * 4);
    bf16*  qkvb  = (bf16*) alloc((size_t)BT * 3 * DM * 2);
    bf16*  tmpb  = (bf16*) alloc((size_t)BT * DM * 2);
    bf16*  ctxb  = (bf16*) alloc((size_t)BT * DM * 2);
    bf16*  hb    = (bf16*) alloc((size_t)BT * 4 * DM * 2);
    bf16*  wteb  = (bf16*) alloc((size_t)VOCAB * DM * 2);
    bf16*  wqkvT = (bf16*) alloc((size_t)NLAYERS * 3 * DM * DM * 2);
    bf16*  wprojT= (bf16*) alloc((size_t)NLAYERS * DM * DM * 2);
    bf16*  wfcT  = (bf16*) alloc((size_t)NLAYERS * 4 * DM * DM * 2);
    bf16*  wfc2T = (bf16*) alloc((size_t)NLAYERS * 4 * DM * DM * 2);
    // loss partials (25.8 MB) alias the ctxb+hb region (31.5 MB, dead after layer loop)
    float2* partials = (float2*)ctxb;

    dim3 tb(32, 8);
    transpose_bf16_kernel<<<dim3(3 * DM / 32, DM / 32, NLAYERS), tb, 0, stream>>>(attn_w, wqkvT, DM, 3 * DM);
    transpose_bf16_kernel<<<dim3(DM / 32, DM / 32, NLAYERS), tb, 0, stream>>>(proj_w, wprojT, DM, DM);
    transpose_bf16_kernel<<<dim3(4 * DM / 32, DM / 32, NLAYERS), tb, 0, stream>>>(fc_w, wfcT, DM, 4 * DM);
    transpose_bf16_kernel<<<dim3(DM / 32, 4 * DM / 32, NLAYERS), tb, 0, stream>>>(fc2_w, wfc2T, 4 * DM, DM);
    {
        size_t n = (size_t)VOCAB * DM;
        tobf16_kernel<<<(unsigned)((n + 255) / 256), 256, 0, stream>>>(wte, wteb, n);
    }

    embed_kernel<<<BT * DM / 4 / 256, 256, 0, stream>>>(inp, wte, wpe, x);

    for (int i = 0; i < NLAYERS; ++i) {
        ln_kernel<<<BT / 4, 256, 0, stream>>>(x, ln1_w + i * DM, ln1_b + i * DM, tmpb);
        gemm_k<GF_OBF16, 0><<<dim3(BT / 128, 3 * DM / 128), 256, 0, stream>>>(
            tmpb, wqkvT + (size_t)i * 3 * DM * DM, attn_b + i * 3 * DM, nullptr,
            qkvb, nullptr, BT, 3 * DM, DM);
        flash_attn_kernel<<<dim3(TSEQ / 128, 4 * NHEADS), 512, 0, stream>>>(qkvb, ctxb);
        gemm_k<0, 1><<<dim3(BT / 128, DM / 128), 256, 0, stream>>>(
            ctxb, wprojT + (size_t)i * DM * DM, proj_b + i * DM, x,
            x, nullptr, BT, DM, DM);
        ln_kernel<<<BT / 4, 256, 0, stream>>>(x, ln2_w + i * DM, ln2_b + i * DM, tmpb);
        gemm_k<GF_GELU | GF_OBF16, 2><<<dim3(BT / 128, 4 * DM / 128), 256, 0, stream>>>(
            tmpb, wfcT + (size_t)i * 4 * DM * DM, fc_b + i * 4 * DM, nullptr,
            hb, nullptr, BT, 4 * DM, DM);
        gemm_k<0, 3><<<dim3(BT / 128, DM / 128), 256, 0, stream>>>(
            hb, wfc2T + (size_t)i * 4 * DM * DM, fc2_b + i * DM, x,
            x, nullptr, BT, DM, 4 * DM);
    }

    ln_kernel<<<BT / 4, 256, 0, stream>>>(x, lnf_w, lnf_b, tmpb);
    gemm_wide<GF_CLAMP | GF_PARTIAL, 4><<<dim3(BT / 128, (VOCAB + 255) / 256), 512, 0, stream>>>(
        tmpb, wteb, nullptr, nullptr, out, partials, BT, VOCAB, DM);
    loss_reduce_kernel<<<BT, 256, 0, stream>>>(partials, out, target, nll);
    loss2_kernel<<<1, 1024, 0, stream>>>(nll, out + (size_t)out_size - 1);
}

// Round 12
// 4106.543 us; speedup vs baseline: 1.0570x; 1.0330x over previous
//
#include <hip/hip_runtime.h>
#include <hip/hip_bf16.h>
#include <cmath>

#define NLAYERS 12
#define NHEADS  12
#define DM      768
#define VOCAB   50257
#define TSEQ    1024
#define BT      4096   // B*T
#define NCHUNK  786    // ceil(VOCAB/64) col-chunks for loss partials

typedef __attribute__((ext_vector_type(4))) float f32x4;
typedef __attribute__((ext_vector_type(8))) short bf16x8;
typedef __attribute__((ext_vector_type(4))) short s16x4;

typedef __hip_bfloat16 bf16;

#define MFMA16(a, b, c) __builtin_amdgcn_mfma_f32_16x16x32_bf16(a, b, c, 0, 0, 0)

// ---------------- helpers ----------------
__device__ __forceinline__ void gload16(const void* g, void* l) {
    __builtin_amdgcn_global_load_lds(
        (const __attribute__((address_space(1))) void*)g,
        (__attribute__((address_space(3))) void*)l, 16, 0, 0);
}

// raw s_barrier with compiler memory fences (no forced vmcnt(0) drain)
__device__ __forceinline__ void wg_barrier() {
    asm volatile("" ::: "memory");
    __builtin_amdgcn_s_barrier();
    asm volatile("" ::: "memory");
}

__device__ __forceinline__ float gelu_tanh(float v) {
    float u = 0.7978845608028654f * (v + 0.044715f * v * v * v);
    return 0.5f * v * (1.0f + tanhf(u));
}

__device__ __forceinline__ short f2bf(float f) {
    bf16 h = (bf16)f;
    return *reinterpret_cast<short*>(&h);
}

struct ushort4s { short a, b, c, d; };

// ---------------- weight prep ----------------
__global__ void transpose_bf16_kernel(const float* __restrict__ in, bf16* __restrict__ out,
                                      int K, int N) {
    __shared__ float tile[32][33];
    size_t lofs = (size_t)blockIdx.z * K * N;
    int k0 = blockIdx.y * 32, n0 = blockIdx.x * 32;
    int tx = threadIdx.x, ty = threadIdx.y;      // 32x8
#pragma unroll
    for (int i = 0; i < 32; i += 8)
        tile[ty + i][tx] = in[lofs + (size_t)(k0 + ty + i) * N + n0 + tx];
    __syncthreads();
#pragma unroll
    for (int i = 0; i < 32; i += 8)
        out[lofs + (size_t)(n0 + ty + i) * K + k0 + tx] = (bf16)tile[tx][ty + i];
}

__global__ void tobf16_kernel(const float* __restrict__ in, bf16* __restrict__ out, size_t n4) {
    size_t i = (size_t)blockIdx.x * 256 + threadIdx.x;
    if (i < n4) {
        float4 f = reinterpret_cast<const float4*>(in)[i];
        s16x4 o = {f2bf(f.x), f2bf(f.y), f2bf(f.z), f2bf(f.w)};
        *reinterpret_cast<s16x4*>(out + i * 4) = o;
    }
}

// ---------------- embedding (fp32 residual stream, float4) ----------------
__global__ void embed_kernel(const int* __restrict__ inp, const float* __restrict__ wte,
                             const float* __restrict__ wpe, float* __restrict__ x) {
    int idx = blockIdx.x * 256 + threadIdx.x;    // over BT*DM/4
    int m = idx / (DM / 4), c4 = idx % (DM / 4);
    int tok = inp[m];
    int t = m & (TSEQ - 1);
    float4 a = reinterpret_cast<const float4*>(wte)[(size_t)tok * (DM / 4) + c4];
    float4 b = reinterpret_cast<const float4*>(wpe)[(size_t)t * (DM / 4) + c4];
    float4 o = {a.x + b.x, a.y + b.y, a.z + b.z, a.w + b.w};
    reinterpret_cast<float4*>(x)[idx] = o;
}

// ---------------- layernorm: one row per WAVE (no block sync) ----------------
__global__ __launch_bounds__(256) void ln_kernel(const float* __restrict__ x,
                                                 const float* __restrict__ w,
                                                 const float* __restrict__ b,
                                                 bf16* __restrict__ y) {
    int tid = threadIdx.x, wv = tid >> 6, lane = tid & 63;
    int row = blockIdx.x * 4 + wv;
    const float4* xr = reinterpret_cast<const float4*>(x + (size_t)row * DM);
    float4 v[3];
    float s = 0.f, q = 0.f;
#pragma unroll
    for (int j = 0; j < 3; ++j) {
        v[j] = xr[lane + 64 * j];
        s += v[j].x + v[j].y + v[j].z + v[j].w;
        q += v[j].x * v[j].x + v[j].y * v[j].y + v[j].z * v[j].z + v[j].w * v[j].w;
    }
#pragma unroll
    for (int o = 1; o < 64; o <<= 1) { s += __shfl_xor(s, o); q += __shfl_xor(q, o); }
    float mu  = s * (1.0f / DM);
    float var = q * (1.0f / DM) - mu * mu;
    float inv = rsqrtf(var + 1e-5f);
#pragma unroll
    for (int j = 0; j < 3; ++j) {
        int c4 = lane + 64 * j;
        float4 wv4 = reinterpret_cast<const float4*>(w)[c4];
        float4 bv4 = reinterpret_cast<const float4*>(b)[c4];
        ushort4s o;
        o.a = f2bf((v[j].x - mu) * inv * wv4.x + bv4.x);
        o.b = f2bf((v[j].y - mu) * inv * wv4.y + bv4.y);
        o.c = f2bf((v[j].z - mu) * inv * wv4.z + bv4.z);
        o.d = f2bf((v[j].w - mu) * inv * wv4.w + bv4.w);
        *reinterpret_cast<ushort4s*>(y + (size_t)row * DM + c4 * 4) = o;
    }
}

#define GF_GELU    1
#define GF_OBF16   2
#define GF_CLAMP   4
#define GF_PARTIAL 8

// ---------------- 128x128 GEMM, 3-buffer 2-ahead prefetch, counted vmcnt ----------------
// 4 gload_lds per tile per thread. Iter t: stage(t+2) -> vmcnt(8) [t landed,
// t+1/t+2 in flight] -> barrier -> compute(t) -> lgkmcnt(0) -> barrier.
// Buffer (t+2)%3 was last read at iter t-1 (two barriers earlier) -> race-free.
template<int FLAGS, int TAG>
__global__ __launch_bounds__(256) void gemm_k(
    const bf16* __restrict__ A, const bf16* __restrict__ Bt,
    const float* __restrict__ bias, const float* __restrict__ resid,
    void* __restrict__ C, float2* __restrict__ partials,
    int M, int N, int K) {
    __shared__ short ldsA[3][128 * 32];
    __shared__ short ldsB[3][128 * 32];
    int tid = threadIdx.x;
    int lane = tid & 63, w = tid >> 6;
    int wm = w >> 1, wn = w & 1;
    int r = lane & 15, kq = lane >> 4;
    int bm = blockIdx.x * 128, bn = blockIdx.y * 128;

    f32x4 acc[4][4] = {};

    auto stage = [&](int buf, int kt) {
        int k0 = kt * 32;
#pragma unroll
        for (int i = 0; i < 2; ++i) {
            int chunk = i * 256 + tid;           // 16B chunk id = row*4 + dest granule
            int row = chunk >> 2;
            int gs = (chunk & 3) ^ ((row >> 1) & 3);   // swizzled source granule
            const bf16* ga = A + (size_t)(bm + row) * K + k0 + gs * 8;
            gload16(ga, &ldsA[buf][(i * 256 + w * 64) * 8]);
            int brow = bn + row;
            const bf16* gb = Bt + (size_t)brow * K + k0 + gs * 8;
            gload16(gb, &ldsB[buf][(i * 256 + w * 64) * 8]);
        }
    };
    auto compute = [&](int buf) {
        bf16x8 af[4], bfr[4];
#pragma unroll
        for (int m = 0; m < 4; ++m) {
            int row = wm * 64 + m * 16 + r;
            af[m] = *reinterpret_cast<bf16x8*>(&ldsA[buf][row * 32 + (kq ^ ((row >> 1) & 3)) * 8]);
        }
#pragma unroll
        for (int n = 0; n < 4; ++n) {
            int row = wn * 64 + n * 16 + r;
            bfr[n] = *reinterpret_cast<bf16x8*>(&ldsB[buf][row * 32 + (kq ^ ((row >> 1) & 3)) * 8]);
        }
        __builtin_amdgcn_s_setprio(1);
#pragma unroll
        for (int m = 0; m < 4; ++m)
#pragma unroll
            for (int n = 0; n < 4; ++n)
                acc[m][n] = MFMA16(af[m], bfr[n], acc[m][n]);
        __builtin_amdgcn_s_setprio(0);
    };

    const int NT = K / 32;
    stage(0, 0);
    stage(1, 1);
    for (int t = 0; t < NT; ++t) {
        if (t + 2 < NT) {
            stage((t + 2) % 3, t + 2);
            asm volatile("s_waitcnt vmcnt(8)" ::: "memory");   // tile t landed
        } else if (t + 1 < NT) {
            asm volatile("s_waitcnt vmcnt(4)" ::: "memory");
        } else {
            asm volatile("s_waitcnt vmcnt(0)" ::: "memory");
        }
        wg_barrier();                    // tile t resident for ALL waves
        compute(t % 3);
        asm volatile("s_waitcnt lgkmcnt(0)" ::: "memory");     // my reads done
        wg_barrier();                    // publish: buffer reusable
    }

    int row0 = bm + wm * 64, col0 = bn + wn * 64;
#pragma unroll
    for (int m = 0; m < 4; ++m) {
#pragma unroll
        for (int n = 0; n < 4; ++n) {
            int col = col0 + n * 16 + r;
#pragma unroll
            for (int rr = 0; rr < 4; ++rr) {
                int row = row0 + m * 16 + kq * 4 + rr;
                float v = acc[m][n][rr];
                if (bias) v += bias[col];
                if (FLAGS & GF_GELU) v = gelu_tanh(v);
                if (resid) v += resid[(size_t)row * N + col];
                if (FLAGS & GF_OBF16) ((bf16*)C)[(size_t)row * N + col] = (bf16)v;
                else                  ((float*)C)[(size_t)row * N + col] = v;
            }
        }
    }
}

// ---------------- 128x256 GEMM, 8 waves x 64x64, 3-buffer 2-ahead (lm_head) ----------------
// 3 gload_lds per tile per thread -> vmcnt(6)/(3)/(0). LDS 72 KB, 2 blocks/CU.
template<int FLAGS, int TAG>
__global__ __launch_bounds__(512, 4) void gemm_wide(
    const bf16* __restrict__ A, const bf16* __restrict__ Bt,
    const float* __restrict__ bias, const float* __restrict__ resid,
    void* __restrict__ C, float2* __restrict__ partials,
    int M, int N, int K) {
    __shared__ short ldsA[3][128 * 32];          // 3 x 8 KB
    __shared__ short ldsB[3][256 * 32];          // 3 x 16 KB
    int tid = threadIdx.x;                       // 0..511
    int lane = tid & 63, w = tid >> 6;
    int wm = w >> 2, wn = w & 3;                 // 2M x 4N waves, 64x64 each
    int r = lane & 15, kq = lane >> 4;
    int bm = blockIdx.x * 128, bn = blockIdx.y * 256;

    f32x4 acc[4][4] = {};

    auto stage = [&](int buf, int kt) {
        int k0 = kt * 32;
        {   // A tile: 512 chunks, 1 per thread
            int row = tid >> 2;
            int gs = (tid & 3) ^ ((row >> 1) & 3);
            gload16(A + (size_t)(bm + row) * K + k0 + gs * 8, &ldsA[buf][tid * 8]);
        }
#pragma unroll
        for (int i = 0; i < 2; ++i) {            // B tile: 1024 chunks, 2 per thread
            int chunk = i * 512 + tid;
            int row = chunk >> 2;
            int gs = (chunk & 3) ^ ((row >> 1) & 3);
            int grow = bn + row;
            if (FLAGS & GF_CLAMP) grow = min(grow, N - 1);
            gload16(Bt + (size_t)grow * K + k0 + gs * 8, &ldsB[buf][chunk * 8]);
        }
    };
    auto compute = [&](int buf) {
        bf16x8 af[4], bfr[4];
#pragma unroll
        for (int m = 0; m < 4; ++m) {
            int row = wm * 64 + m * 16 + r;
            af[m] = *reinterpret_cast<bf16x8*>(&ldsA[buf][row * 32 + (kq ^ ((row >> 1) & 3)) * 8]);
        }
#pragma unroll
        for (int n = 0; n < 4; ++n) {
            int row = wn * 64 + n * 16 + r;
            bfr[n] = *reinterpret_cast<bf16x8*>(&ldsB[buf][row * 32 + (kq ^ ((row >> 1) & 3)) * 8]);
        }
        __builtin_amdgcn_s_setprio(1);
#pragma unroll
        for (int m = 0; m < 4; ++m)
#pragma unroll
            for (int n = 0; n < 4; ++n)
                acc[m][n] = MFMA16(af[m], bfr[n], acc[m][n]);
        __builtin_amdgcn_s_setprio(0);
    };

    const int NT = K / 32;                       // 24
    stage(0, 0);
    stage(1, 1);
    for (int t = 0; t < NT; ++t) {
        if (t + 2 < NT) {
            stage((t + 2) % 3, t + 2);
            asm volatile("s_waitcnt vmcnt(6)" ::: "memory");   // tile t landed
        } else if (t + 1 < NT) {
            asm volatile("s_waitcnt vmcnt(3)" ::: "memory");
        } else {
            asm volatile("s_waitcnt vmcnt(0)" ::: "memory");
        }
        wg_barrier();
        compute(t % 3);
        asm volatile("s_waitcnt lgkmcnt(0)" ::: "memory");
        wg_barrier();
    }

    int row0 = bm + wm * 64, col0 = bn + wn * 64;
#pragma unroll
    for (int m = 0; m < 4; ++m) {
#pragma unroll
        for (int n = 0; n < 4; ++n) {
            int col = col0 + n * 16 + r;
            if (col < N) {
#pragma unroll
                for (int rr = 0; rr < 4; ++rr) {
                    int row = row0 + m * 16 + kq * 4 + rr;
                    float v = acc[m][n][rr];
                    if (bias) v += bias[col];
                    if (FLAGS & GF_GELU) v = gelu_tanh(v);
                    if (resid) v += resid[(size_t)row * N + col];
                    if (FLAGS & GF_OBF16) ((bf16*)C)[(size_t)row * N + col] = (bf16)v;
                    else                  ((float*)C)[(size_t)row * N + col] = v;
                }
            }
        }
    }

    if (FLAGS & GF_PARTIAL) {
        int chunk = (bn >> 6) + wn;              // 64-col chunk index
        if (chunk < NCHUNK) {
#pragma unroll
            for (int m = 0; m < 4; ++m) {
#pragma unroll
                for (int rr = 0; rr < 4; ++rr) {
                    float vals[4], mx = -INFINITY;
#pragma unroll
                    for (int n = 0; n < 4; ++n) {
                        int col = col0 + n * 16 + r;
                        float v = (col < N) ? acc[m][n][rr] : -INFINITY;
                        vals[n] = v;
                        mx = fmaxf(mx, v);
                    }
#pragma unroll
                    for (int o = 1; o < 16; o <<= 1) mx = fmaxf(mx, __shfl_xor(mx, o));
                    float sum = 0.f;
#pragma unroll
                    for (int n = 0; n < 4; ++n)
                        if (vals[n] > -INFINITY) sum += __expf(vals[n] - mx);
#pragma unroll
                    for (int o = 1; o < 16; o <<= 1) sum += __shfl_xor(sum, o);
                    if (r == 0) {
                        int row = row0 + m * 16 + kq * 4 + rr;
                        partials[(size_t)row * NCHUNK + chunk] = make_float2(mx, sum);
                    }
                }
            }
        }
    }
}

// ---------------- flash attention: QBLK=128, 8 waves, reg-staged K/V ----------------
__global__ __launch_bounds__(512, 4) void flash_attn_kernel(const bf16* __restrict__ qkv,
                                                            bf16* __restrict__ ctx) {
    __shared__ short Ks[128 * 64];       // K tile [kv][64 d], granule ^= kv&7
    __shared__ short Vt[64 * 128];       // V^T tile [d][128 kv], granule ^= d&7
    __shared__ short Ps[8][16][132];     // per-wave P tile [qrow][kv], padded

    int tid = threadIdx.x, lane = tid & 63, w = tid >> 6;   // 8 waves
    int r = lane & 15, kq = lane >> 4;
    int qt = (int)gridDim.x - 1 - (int)blockIdx.x;           // longest first
    int q0 = qt * 128;
    int bh = blockIdx.y;
    int b = bh / NHEADS, h = bh % NHEADS;
    const int RS = 3 * DM;

    const bf16* qbase = qkv + (size_t)(b * TSEQ + q0 + w * 16 + r) * RS + h * 64;
    bf16x8 qf[2];
    qf[0] = *reinterpret_cast<const bf16x8*>(qbase + kq * 8);
    qf[1] = *reinterpret_cast<const bf16x8*>(qbase + 32 + kq * 8);

    f32x4 of[4] = {};
    float mrow[4] = {-INFINITY, -INFINITY, -INFINITY, -INFINITY};
    float lrow[4] = {};

    int stid = tid & 255;
    int kvq = stid >> 3;                 // 0..31 -> kv rows kvq*4..+3
    int d0 = (stid & 7) * 8;
    bool isK = tid < 256;
    const bf16* sb0 = qkv + (size_t)(b * TSEQ) * RS + (isK ? DM : 2 * DM) + h * 64;
    bf16x8 r0, r1, r2, r3;

    auto loadKV = [&](int t) {
        const bf16* p = sb0 + (size_t)(t * 128 + kvq * 4) * RS + d0;
        r0 = *reinterpret_cast<const bf16x8*>(p);
        r1 = *reinterpret_cast<const bf16x8*>(p + RS);
        r2 = *reinterpret_cast<const bf16x8*>(p + 2 * RS);
        r3 = *reinterpret_cast<const bf16x8*>(p + 3 * RS);
    };
    auto writeKV = [&]() {
        if (isK) {
            bf16x8 rs[4] = {r0, r1, r2, r3};
#pragma unroll
            for (int j = 0; j < 4; ++j) {
                int kv = kvq * 4 + j;
                int pg = (stid & 7) ^ (kv & 7);
                *reinterpret_cast<bf16x8*>(&Ks[kv * 64 + pg * 8]) = rs[j];
            }
        } else {
            int lg = kvq >> 1, half = kvq & 1;
#pragma unroll
            for (int jj = 0; jj < 8; ++jj) {
                int d = d0 + jj;
                int phys = lg ^ (d & 7);
                s16x4 pk = {r0[jj], r1[jj], r2[jj], r3[jj]};
                *reinterpret_cast<s16x4*>(&Vt[d * 128 + phys * 8 + half * 4]) = pk;
            }
        }
    };

    int ntiles = qt + 1;
    loadKV(0);
    for (int t = 0; t < ntiles; ++t) {
        __syncthreads();                 // prior tile's LDS reads done
        writeKV();
        __syncthreads();                 // publish Ks/Vt
        if (t + 1 < ntiles) loadKV(t + 1);   // lands under this tile's compute

        int kv0 = t * 128;
        // ---- QK^T: 16 MFMA ----
        f32x4 sf[8];
#pragma unroll
        for (int n = 0; n < 8; ++n) sf[n] = (f32x4){0.f, 0.f, 0.f, 0.f};
        __builtin_amdgcn_s_setprio(1);
#pragma unroll
        for (int n = 0; n < 8; ++n) {
            int row = n * 16 + r;
#pragma unroll
            for (int kt = 0; kt < 2; ++kt) {
                int gran = (kt * 4 + kq) ^ (row & 7);
                bf16x8 kf = *reinterpret_cast<bf16x8*>(&Ks[row * 64 + gran * 8]);
                sf[n] = MFMA16(qf[kt], kf, sf[n]);
            }
        }
        __builtin_amdgcn_s_setprio(0);

        // ---- online softmax over 128 cols ----
        bool diag = (kv0 + 128 > q0);
        float alpha[4];
#pragma unroll
        for (int rr = 0; rr < 4; ++rr) {
            int qrow = q0 + w * 16 + kq * 4 + rr;
            float vals[8];
            float mx = mrow[rr];
#pragma unroll
            for (int n = 0; n < 8; ++n) {
                float v = sf[n][rr] * 0.125f;
                if (diag && (kv0 + n * 16 + r) > qrow) v = -INFINITY;
                vals[n] = v;
                mx = fmaxf(mx, v);
            }
#pragma unroll
            for (int o = 1; o < 16; o <<= 1) mx = fmaxf(mx, __shfl_xor(mx, o));
            float al = __expf(mrow[rr] - mx);
            float sum = 0.f;
#pragma unroll
            for (int n = 0; n < 8; ++n) {
                float p = __expf(vals[n] - mx);
                vals[n] = p;
                sum += p;
            }
#pragma unroll
            for (int o = 1; o < 16; o <<= 1) sum += __shfl_xor(sum, o);
            mrow[rr] = mx;
            lrow[rr] = lrow[rr] * al + sum;
            alpha[rr] = al;
#pragma unroll
            for (int n = 0; n < 8; ++n) Ps[w][kq * 4 + rr][n * 16 + r] = f2bf(vals[n]);
        }
#pragma unroll
        for (int n = 0; n < 4; ++n)
#pragma unroll
            for (int rr = 0; rr < 4; ++rr) of[n][rr] *= alpha[rr];

        // ---- PV: 16 MFMA ----
        __builtin_amdgcn_s_setprio(1);
#pragma unroll
        for (int kt = 0; kt < 4; ++kt) {
            bf16x8 pa = *reinterpret_cast<bf16x8*>(&Ps[w][r][kt * 32 + kq * 8]);
#pragma unroll
            for (int n = 0; n < 4; ++n) {
                int row = n * 16 + r;
                int gran = (kt * 4 + kq) ^ (row & 7);
                bf16x8 vf = *reinterpret_cast<bf16x8*>(&Vt[row * 128 + gran * 8]);
                of[n] = MFMA16(pa, vf, of[n]);
            }
        }
        __builtin_amdgcn_s_setprio(0);
    }

    // ---- epilogue ----
#pragma unroll
    for (int rr = 0; rr < 4; ++rr) {
        float inv = 1.0f / lrow[rr];
        int qrow = q0 + w * 16 + kq * 4 + rr;
        bf16* cb = ctx + (size_t)(b * TSEQ + qrow) * DM + h * 64;
#pragma unroll
        for (int n = 0; n < 4; ++n) cb[n * 16 + r] = (bf16)(of[n][rr] * inv);
    }
}

// ---------------- loss: merge per-chunk partials ----------------
__global__ __launch_bounds__(256) void loss_reduce_kernel(const float2* __restrict__ partials,
                                                          const float* __restrict__ logits,
                                                          const int* __restrict__ target,
                                                          float* __restrict__ nll) {
    int row = blockIdx.x, tid = threadIdx.x;
    const float2* pr = partials + (size_t)row * NCHUNK;
    float m = -INFINITY, s = 0.f;
    for (int c = tid; c < NCHUNK; c += 256) {
        float2 p = pr[c];
        if (p.x > m) { s = s * __expf(m - p.x) + p.y; m = p.x; }
        else         { s += p.y * __expf(p.x - m); }
    }
    __shared__ float sm[256], ssum[256];
    sm[tid] = m; ssum[tid] = s; __syncthreads();
    for (int o = 128; o; o >>= 1) {
        if (tid < o) {
            float m2 = sm[tid + o], s2 = ssum[tid + o];
            float mm = fmaxf(sm[tid], m2);
            ssum[tid] = ssum[tid] * __expf(sm[tid] - mm) + s2 * __expf(m2 - mm);
            sm[tid] = mm;
        }
        __syncthreads();
    }
    if (tid == 0) {
        float lse = sm[0] + logf(ssum[0]);
        nll[row] = lse - logits[(size_t)row * VOCAB + target[row]];
    }
}

__global__ void loss2_kernel(const float* __restrict__ nll, float* __restrict__ loss) {
    int tid = threadIdx.x;
    float s = 0.f;
    for (int i = tid; i < BT; i += 1024) s += nll[i];
    __shared__ float r[1024];
    r[tid] = s; __syncthreads();
    for (int o = 512; o; o >>= 1) { if (tid < o) r[tid] += r[tid + o]; __syncthreads(); }
    if (tid == 0) *loss = r[0] * (1.0f / BT);
}

// ---------------- launcher ----------------
extern "C" void kernel_launch(void* const* d_in, const int* in_sizes, int n_in,
                              void* d_out, int out_size, void* d_ws, size_t ws_size,
                              hipStream_t stream) {
    const int*   inp    = (const int*)  d_in[0];
    const int*   target = (const int*)  d_in[1];
    const float* wte    = (const float*)d_in[2];
    const float* wpe    = (const float*)d_in[3];
    const float* ln1_w  = (const float*)d_in[4];
    const float* ln1_b  = (const float*)d_in[5];
    const float* attn_w = (const float*)d_in[6];
    const float* attn_b = (const float*)d_in[7];
    const float* proj_w = (const float*)d_in[8];
    const float* proj_b = (const float*)d_in[9];
    const float* ln2_w  = (const float*)d_in[10];
    const float* ln2_b  = (const float*)d_in[11];
    const float* fc_w   = (const float*)d_in[12];
    const float* fc_b   = (const float*)d_in[13];
    const float* fc2_w  = (const float*)d_in[14];
    const float* fc2_b  = (const float*)d_in[15];
    const float* lnf_w  = (const float*)d_in[16];
    const float* lnf_b  = (const float*)d_in[17];
    float* out = (float*)d_out;

    char* p = (char*)d_ws;
    auto alloc = [&](size_t bytes) { char* q = p; p += (bytes + 255) & ~(size_t)255; return q; };
    float* x     = (float*)alloc((size_t)BT * DM * 4);
    float* nll   = (float*)alloc((size_t)BT * 4);
    bf16*  qkvb  = (bf16*) alloc((size_t)BT * 3 * DM * 2);
    bf16*  tmpb  = (bf16*) alloc((size_t)BT * DM * 2);
    bf16*  ctxb  = (bf16*) alloc((size_t)BT * DM * 2);
    bf16*  hb    = (bf16*) alloc((size_t)BT * 4 * DM * 2);
    bf16*  wteb  = (bf16*) alloc((size_t)VOCAB * DM * 2);
    bf16*  wqkvT = (bf16*) alloc((size_t)NLAYERS * 3 * DM * DM * 2);
    bf16*  wprojT= (bf16*) alloc((size_t)NLAYERS * DM * DM * 2);
    bf16*  wfcT  = (bf16*) alloc((size_t)NLAYERS * 4 * DM * DM * 2);
    bf16*  wfc2T = (bf16*) alloc((size_t)NLAYERS * 4 * DM * DM * 2);
    // loss partials (25.8 MB) alias the ctxb+hb region (31.5 MB, dead after layer loop)
    float2* partials = (float2*)ctxb;

    dim3 tb(32, 8);
    transpose_bf16_kernel<<<dim3(3 * DM / 32, DM / 32, NLAYERS), tb, 0, stream>>>(attn_w, wqkvT, DM, 3 * DM);
    transpose_bf16_kernel<<<dim3(DM / 32, DM / 32, NLAYERS), tb, 0, stream>>>(proj_w, wprojT, DM, DM);
    transpose_bf16_kernel<<<dim3(4 * DM / 32, DM / 32, NLAYERS), tb, 0, stream>>>(fc_w, wfcT, DM, 4 * DM);
    transpose_bf16_kernel<<<dim3(DM / 32, 4 * DM / 32, NLAYERS), tb, 0, stream>>>(fc2_w, wfc2T, 4 * DM, DM);
    {
        size_t n4 = (size_t)VOCAB * DM / 4;
        tobf16_kernel<<<(unsigned)((n4 + 255) / 256), 256, 0, stream>>>(wte, wteb, n4);
    }

    embed_kernel<<<BT * DM / 4 / 256, 256, 0, stream>>>(inp, wte, wpe, x);

    for (int i = 0; i < NLAYERS; ++i) {
        ln_kernel<<<BT / 4, 256, 0, stream>>>(x, ln1_w + i * DM, ln1_b + i * DM, tmpb);
        gemm_k<GF_OBF16, 0><<<dim3(BT / 128, 3 * DM / 128), 256, 0, stream>>>(
            tmpb, wqkvT + (size_t)i * 3 * DM * DM, attn_b + i * 3 * DM, nullptr,
            qkvb, nullptr, BT, 3 * DM, DM);
        flash_attn_kernel<<<dim3(TSEQ / 128, 4 * NHEADS), 512, 0, stream>>>(qkvb, ctxb);
        gemm_k<0, 1><<<dim3(BT / 128, DM / 128), 256, 0, stream>>>(
            ctxb, wprojT + (size_t)i * DM * DM, proj_b + i * DM, x,
            x, nullptr, BT, DM, DM);
        ln_kernel<<<BT / 4, 256, 0, stream>>>(x, ln2_w + i * DM, ln2_b + i * DM, tmpb);
        gemm_k<GF_GELU | GF_OBF16, 2><<<dim3(BT / 128, 4 * DM / 128), 256, 0, stream>>>(
            tmpb, wfcT + (size_t)i * 4 * DM * DM, fc_b + i * 4 * DM, nullptr,
            hb, nullptr, BT, 4 * DM, DM);
        gemm_k<0, 3><<<dim3(BT / 128, DM / 128), 256, 0, stream>>>(
            hb, wfc2T + (size_t)i * 4 * DM * DM, fc2_b + i * DM, x,
            x, nullptr, BT, DM, 4 * DM);
    }

    ln_kernel<<<BT / 4, 256, 0, stream>>>(x, lnf_w, lnf_b, tmpb);
    gemm_wide<GF_CLAMP | GF_PARTIAL, 4><<<dim3(BT / 128, (VOCAB + 255) / 256), 512, 0, stream>>>(
        tmpb, wteb, nullptr, nullptr, out, partials, BT, VOCAB, DM);
    loss_reduce_kernel<<<BT, 256, 0, stream>>>(partials, out, target, nll);
    loss2_kernel<<<1, 1024, 0, stream>>>(nll, out + (size_t)out_size - 1);
}

// Round 13
// 4030.591 us; speedup vs baseline: 1.0770x; 1.0188x over previous
//
#include <hip/hip_runtime.h>
#include <hip/hip_bf16.h>
#include <cmath>

#define NLAYERS 12
#define NHEADS  12
#define DM      768
#define VOCAB   50257
#define TSEQ    1024
#define BT      4096   // B*T
#define NCHUNK  786    // ceil(VOCAB/64) col-chunks for loss partials

typedef __attribute__((ext_vector_type(4))) float f32x4;
typedef __attribute__((ext_vector_type(8))) short bf16x8;
typedef __attribute__((ext_vector_type(4))) short s16x4;

typedef __hip_bfloat16 bf16;

#define MFMA16(a, b, c) __builtin_amdgcn_mfma_f32_16x16x32_bf16(a, b, c, 0, 0, 0)

// ---------------- helpers ----------------
__device__ __forceinline__ void gload16(const void* g, void* l) {
    __builtin_amdgcn_global_load_lds(
        (const __attribute__((address_space(1))) void*)g,
        (__attribute__((address_space(3))) void*)l, 16, 0, 0);
}

// raw s_barrier with compiler memory fences (no forced vmcnt(0) drain)
__device__ __forceinline__ void wg_barrier() {
    asm volatile("" ::: "memory");
    __builtin_amdgcn_s_barrier();
    asm volatile("" ::: "memory");
}

__device__ __forceinline__ float gelu_tanh(float v) {
    float u = 0.7978845608028654f * (v + 0.044715f * v * v * v);
    return 0.5f * v * (1.0f + tanhf(u));
}

__device__ __forceinline__ short f2bf(float f) {
    bf16 h = (bf16)f;
    return *reinterpret_cast<short*>(&h);
}

// ---- DPP 16-lane butterfly reductions (VALU-speed, no LDS/bpermute) ----
// quad_perm[1,0,3,2]=0xB1, quad_perm[2,3,0,1]=0x4E, row_half_mirror=0x141,
// row_mirror=0x140. All within 16-lane rows; all lanes active at call sites.
template<int CTRL>
__device__ __forceinline__ float dpp_mov(float x) {
    int i = __builtin_bit_cast(int, x);
    i = __builtin_amdgcn_mov_dpp(i, CTRL, 0xF, 0xF, false);
    return __builtin_bit_cast(float, i);
}
__device__ __forceinline__ float dpp_max16(float x) {
    x = fmaxf(x, dpp_mov<0xB1>(x));
    x = fmaxf(x, dpp_mov<0x4E>(x));
    x = fmaxf(x, dpp_mov<0x141>(x));
    x = fmaxf(x, dpp_mov<0x140>(x));
    return x;
}
__device__ __forceinline__ float dpp_sum16(float x) {
    x += dpp_mov<0xB1>(x);
    x += dpp_mov<0x4E>(x);
    x += dpp_mov<0x141>(x);
    x += dpp_mov<0x140>(x);
    return x;
}

struct ushort4s { short a, b, c, d; };

// ---------------- weight prep ----------------
__global__ void transpose_bf16_kernel(const float* __restrict__ in, bf16* __restrict__ out,
                                      int K, int N) {
    __shared__ float tile[32][33];
    size_t lofs = (size_t)blockIdx.z * K * N;
    int k0 = blockIdx.y * 32, n0 = blockIdx.x * 32;
    int tx = threadIdx.x, ty = threadIdx.y;      // 32x8
#pragma unroll
    for (int i = 0; i < 32; i += 8)
        tile[ty + i][tx] = in[lofs + (size_t)(k0 + ty + i) * N + n0 + tx];
    __syncthreads();
#pragma unroll
    for (int i = 0; i < 32; i += 8)
        out[lofs + (size_t)(n0 + ty + i) * K + k0 + tx] = (bf16)tile[tx][ty + i];
}

__global__ void tobf16_kernel(const float* __restrict__ in, bf16* __restrict__ out, size_t n4) {
    size_t i = (size_t)blockIdx.x * 256 + threadIdx.x;
    if (i < n4) {
        float4 f = reinterpret_cast<const float4*>(in)[i];
        s16x4 o = {f2bf(f.x), f2bf(f.y), f2bf(f.z), f2bf(f.w)};
        *reinterpret_cast<s16x4*>(out + i * 4) = o;
    }
}

// ---------------- embedding (fp32 residual stream, float4) ----------------
__global__ void embed_kernel(const int* __restrict__ inp, const float* __restrict__ wte,
                             const float* __restrict__ wpe, float* __restrict__ x) {
    int idx = blockIdx.x * 256 + threadIdx.x;    // over BT*DM/4
    int m = idx / (DM / 4), c4 = idx % (DM / 4);
    int tok = inp[m];
    int t = m & (TSEQ - 1);
    float4 a = reinterpret_cast<const float4*>(wte)[(size_t)tok * (DM / 4) + c4];
    float4 b = reinterpret_cast<const float4*>(wpe)[(size_t)t * (DM / 4) + c4];
    float4 o = {a.x + b.x, a.y + b.y, a.z + b.z, a.w + b.w};
    reinterpret_cast<float4*>(x)[idx] = o;
}

// ---------------- layernorm: one row per WAVE (no block sync) ----------------
__global__ __launch_bounds__(256) void ln_kernel(const float* __restrict__ x,
                                                 const float* __restrict__ w,
                                                 const float* __restrict__ b,
                                                 bf16* __restrict__ y) {
    int tid = threadIdx.x, wv = tid >> 6, lane = tid & 63;
    int row = blockIdx.x * 4 + wv;
    const float4* xr = reinterpret_cast<const float4*>(x + (size_t)row * DM);
    float4 v[3];
    float s = 0.f, q = 0.f;
#pragma unroll
    for (int j = 0; j < 3; ++j) {
        v[j] = xr[lane + 64 * j];
        s += v[j].x + v[j].y + v[j].z + v[j].w;
        q += v[j].x * v[j].x + v[j].y * v[j].y + v[j].z * v[j].z + v[j].w * v[j].w;
    }
#pragma unroll
    for (int o = 1; o < 64; o <<= 1) { s += __shfl_xor(s, o); q += __shfl_xor(q, o); }
    float mu  = s * (1.0f / DM);
    float var = q * (1.0f / DM) - mu * mu;
    float inv = rsqrtf(var + 1e-5f);
#pragma unroll
    for (int j = 0; j < 3; ++j) {
        int c4 = lane + 64 * j;
        float4 wv4 = reinterpret_cast<const float4*>(w)[c4];
        float4 bv4 = reinterpret_cast<const float4*>(b)[c4];
        ushort4s o;
        o.a = f2bf((v[j].x - mu) * inv * wv4.x + bv4.x);
        o.b = f2bf((v[j].y - mu) * inv * wv4.y + bv4.y);
        o.c = f2bf((v[j].z - mu) * inv * wv4.z + bv4.z);
        o.d = f2bf((v[j].w - mu) * inv * wv4.w + bv4.w);
        *reinterpret_cast<ushort4s*>(y + (size_t)row * DM + c4 * 4) = o;
    }
}

#define GF_GELU    1
#define GF_OBF16   2
#define GF_CLAMP   4
#define GF_PARTIAL 8

// ---------------- 128x128 GEMM, 3-buffer 2-ahead prefetch, counted vmcnt ----------------
template<int FLAGS, int TAG>
__global__ __launch_bounds__(256) void gemm_k(
    const bf16* __restrict__ A, const bf16* __restrict__ Bt,
    const float* __restrict__ bias, const float* __restrict__ resid,
    void* __restrict__ C, float2* __restrict__ partials,
    int M, int N, int K) {
    __shared__ short ldsA[3][128 * 32];
    __shared__ short ldsB[3][128 * 32];
    int tid = threadIdx.x;
    int lane = tid & 63, w = tid >> 6;
    int wm = w >> 1, wn = w & 1;
    int r = lane & 15, kq = lane >> 4;
    int bm = blockIdx.x * 128, bn = blockIdx.y * 128;

    f32x4 acc[4][4] = {};

    auto stage = [&](int buf, int kt) {
        int k0 = kt * 32;
#pragma unroll
        for (int i = 0; i < 2; ++i) {
            int chunk = i * 256 + tid;           // 16B chunk id = row*4 + dest granule
            int row = chunk >> 2;
            int gs = (chunk & 3) ^ ((row >> 1) & 3);   // swizzled source granule
            const bf16* ga = A + (size_t)(bm + row) * K + k0 + gs * 8;
            gload16(ga, &ldsA[buf][(i * 256 + w * 64) * 8]);
            int brow = bn + row;
            const bf16* gb = Bt + (size_t)brow * K + k0 + gs * 8;
            gload16(gb, &ldsB[buf][(i * 256 + w * 64) * 8]);
        }
    };
    auto compute = [&](int buf) {
        bf16x8 af[4], bfr[4];
#pragma unroll
        for (int m = 0; m < 4; ++m) {
            int row = wm * 64 + m * 16 + r;
            af[m] = *reinterpret_cast<bf16x8*>(&ldsA[buf][row * 32 + (kq ^ ((row >> 1) & 3)) * 8]);
        }
#pragma unroll
        for (int n = 0; n < 4; ++n) {
            int row = wn * 64 + n * 16 + r;
            bfr[n] = *reinterpret_cast<bf16x8*>(&ldsB[buf][row * 32 + (kq ^ ((row >> 1) & 3)) * 8]);
        }
        __builtin_amdgcn_s_setprio(1);
#pragma unroll
        for (int m = 0; m < 4; ++m)
#pragma unroll
            for (int n = 0; n < 4; ++n)
                acc[m][n] = MFMA16(af[m], bfr[n], acc[m][n]);
        __builtin_amdgcn_s_setprio(0);
    };

    const int NT = K / 32;
    stage(0, 0);
    stage(1, 1);
    for (int t = 0; t < NT; ++t) {
        if (t + 2 < NT) {
            stage((t + 2) % 3, t + 2);
            asm volatile("s_waitcnt vmcnt(8)" ::: "memory");   // tile t landed
        } else if (t + 1 < NT) {
            asm volatile("s_waitcnt vmcnt(4)" ::: "memory");
        } else {
            asm volatile("s_waitcnt vmcnt(0)" ::: "memory");
        }
        wg_barrier();                    // tile t resident for ALL waves
        compute(t % 3);
        asm volatile("s_waitcnt lgkmcnt(0)" ::: "memory");     // my reads done
        wg_barrier();                    // publish: buffer reusable
    }

    int row0 = bm + wm * 64, col0 = bn + wn * 64;
#pragma unroll
    for (int m = 0; m < 4; ++m) {
#pragma unroll
        for (int n = 0; n < 4; ++n) {
            int col = col0 + n * 16 + r;
#pragma unroll
            for (int rr = 0; rr < 4; ++rr) {
                int row = row0 + m * 16 + kq * 4 + rr;
                float v = acc[m][n][rr];
                if (bias) v += bias[col];
                if (FLAGS & GF_GELU) v = gelu_tanh(v);
                if (resid) v += resid[(size_t)row * N + col];
                if (FLAGS & GF_OBF16) ((bf16*)C)[(size_t)row * N + col] = (bf16)v;
                else                  ((float*)C)[(size_t)row * N + col] = v;
            }
        }
    }
}

// ---------------- 128x256 GEMM, 8 waves x 64x64, 3-buffer 2-ahead (lm_head) ----------------
template<int FLAGS, int TAG>
__global__ __launch_bounds__(512, 4) void gemm_wide(
    const bf16* __restrict__ A, const bf16* __restrict__ Bt,
    const float* __restrict__ bias, const float* __restrict__ resid,
    void* __restrict__ C, float2* __restrict__ partials,
    int M, int N, int K) {
    __shared__ short ldsA[3][128 * 32];          // 3 x 8 KB
    __shared__ short ldsB[3][256 * 32];          // 3 x 16 KB
    int tid = threadIdx.x;                       // 0..511
    int lane = tid & 63, w = tid >> 6;
    int wm = w >> 2, wn = w & 3;                 // 2M x 4N waves, 64x64 each
    int r = lane & 15, kq = lane >> 4;
    int bm = blockIdx.x * 128, bn = blockIdx.y * 256;

    f32x4 acc[4][4] = {};

    auto stage = [&](int buf, int kt) {
        int k0 = kt * 32;
        {   // A tile: 512 chunks, 1 per thread
            int row = tid >> 2;
            int gs = (tid & 3) ^ ((row >> 1) & 3);
            gload16(A + (size_t)(bm + row) * K + k0 + gs * 8, &ldsA[buf][tid * 8]);
        }
#pragma unroll
        for (int i = 0; i < 2; ++i) {            // B tile: 1024 chunks, 2 per thread
            int chunk = i * 512 + tid;
            int row = chunk >> 2;
            int gs = (chunk & 3) ^ ((row >> 1) & 3);
            int grow = bn + row;
            if (FLAGS & GF_CLAMP) grow = min(grow, N - 1);
            gload16(Bt + (size_t)grow * K + k0 + gs * 8, &ldsB[buf][chunk * 8]);
        }
    };
    auto compute = [&](int buf) {
        bf16x8 af[4], bfr[4];
#pragma unroll
        for (int m = 0; m < 4; ++m) {
            int row = wm * 64 + m * 16 + r;
            af[m] = *reinterpret_cast<bf16x8*>(&ldsA[buf][row * 32 + (kq ^ ((row >> 1) & 3)) * 8]);
        }
#pragma unroll
        for (int n = 0; n < 4; ++n) {
            int row = wn * 64 + n * 16 + r;
            bfr[n] = *reinterpret_cast<bf16x8*>(&ldsB[buf][row * 32 + (kq ^ ((row >> 1) & 3)) * 8]);
        }
        __builtin_amdgcn_s_setprio(1);
#pragma unroll
        for (int m = 0; m < 4; ++m)
#pragma unroll
            for (int n = 0; n < 4; ++n)
                acc[m][n] = MFMA16(af[m], bfr[n], acc[m][n]);
        __builtin_amdgcn_s_setprio(0);
    };

    const int NT = K / 32;                       // 24
    stage(0, 0);
    stage(1, 1);
    for (int t = 0; t < NT; ++t) {
        if (t + 2 < NT) {
            stage((t + 2) % 3, t + 2);
            asm volatile("s_waitcnt vmcnt(6)" ::: "memory");   // tile t landed
        } else if (t + 1 < NT) {
            asm volatile("s_waitcnt vmcnt(3)" ::: "memory");
        } else {
            asm volatile("s_waitcnt vmcnt(0)" ::: "memory");
        }
        wg_barrier();
        compute(t % 3);
        asm volatile("s_waitcnt lgkmcnt(0)" ::: "memory");
        wg_barrier();
    }

    int row0 = bm + wm * 64, col0 = bn + wn * 64;
#pragma unroll
    for (int m = 0; m < 4; ++m) {
#pragma unroll
        for (int n = 0; n < 4; ++n) {
            int col = col0 + n * 16 + r;
            if (col < N) {
#pragma unroll
                for (int rr = 0; rr < 4; ++rr) {
                    int row = row0 + m * 16 + kq * 4 + rr;
                    float v = acc[m][n][rr];
                    if (bias) v += bias[col];
                    if (FLAGS & GF_GELU) v = gelu_tanh(v);
                    if (resid) v += resid[(size_t)row * N + col];
                    if (FLAGS & GF_OBF16) ((bf16*)C)[(size_t)row * N + col] = (bf16)v;
                    else                  ((float*)C)[(size_t)row * N + col] = v;
                }
            }
        }
    }

    if (FLAGS & GF_PARTIAL) {
        int chunk = (bn >> 6) + wn;              // 64-col chunk index
        if (chunk < NCHUNK) {
#pragma unroll
            for (int m = 0; m < 4; ++m) {
#pragma unroll
                for (int rr = 0; rr < 4; ++rr) {
                    float vals[4], mx = -INFINITY;
#pragma unroll
                    for (int n = 0; n < 4; ++n) {
                        int col = col0 + n * 16 + r;
                        float v = (col < N) ? acc[m][n][rr] : -INFINITY;
                        vals[n] = v;
                        mx = fmaxf(mx, v);
                    }
                    mx = dpp_max16(mx);
                    float sum = 0.f;
#pragma unroll
                    for (int n = 0; n < 4; ++n)
                        if (vals[n] > -INFINITY) sum += __expf(vals[n] - mx);
                    sum = dpp_sum16(sum);
                    if (r == 0) {
                        int row = row0 + m * 16 + kq * 4 + rr;
                        partials[(size_t)row * NCHUNK + chunk] = make_float2(mx, sum);
                    }
                }
            }
        }
    }
}

// ---------------- flash attention: QBLK=128, 8 waves, reg-staged K/V, DPP softmax ----------------
__global__ __launch_bounds__(512, 4) void flash_attn_kernel(const bf16* __restrict__ qkv,
                                                            bf16* __restrict__ ctx) {
    __shared__ short Ks[128 * 64];       // K tile [kv][64 d], granule ^= kv&7
    __shared__ short Vt[64 * 128];       // V^T tile [d][128 kv], granule ^= d&7
    __shared__ short Ps[8][16][132];     // per-wave P tile [qrow][kv], padded

    int tid = threadIdx.x, lane = tid & 63, w = tid >> 6;   // 8 waves
    int r = lane & 15, kq = lane >> 4;
    int qt = (int)gridDim.x - 1 - (int)blockIdx.x;           // longest first
    int q0 = qt * 128;
    int bh = blockIdx.y;
    int b = bh / NHEADS, h = bh % NHEADS;
    const int RS = 3 * DM;

    const bf16* qbase = qkv + (size_t)(b * TSEQ + q0 + w * 16 + r) * RS + h * 64;
    bf16x8 qf[2];
    qf[0] = *reinterpret_cast<const bf16x8*>(qbase + kq * 8);
    qf[1] = *reinterpret_cast<const bf16x8*>(qbase + 32 + kq * 8);

    f32x4 of[4] = {};
    float mrow[4] = {-INFINITY, -INFINITY, -INFINITY, -INFINITY};
    float lrow[4] = {};

    int stid = tid & 255;
    int kvq = stid >> 3;                 // 0..31 -> kv rows kvq*4..+3
    int d0 = (stid & 7) * 8;
    bool isK = tid < 256;
    const bf16* sb0 = qkv + (size_t)(b * TSEQ) * RS + (isK ? DM : 2 * DM) + h * 64;
    bf16x8 r0, r1, r2, r3;

    auto loadKV = [&](int t) {
        const bf16* p = sb0 + (size_t)(t * 128 + kvq * 4) * RS + d0;
        r0 = *reinterpret_cast<const bf16x8*>(p);
        r1 = *reinterpret_cast<const bf16x8*>(p + RS);
        r2 = *reinterpret_cast<const bf16x8*>(p + 2 * RS);
        r3 = *reinterpret_cast<const bf16x8*>(p + 3 * RS);
    };
    auto writeKV = [&]() {
        if (isK) {
            bf16x8 rs[4] = {r0, r1, r2, r3};
#pragma unroll
            for (int j = 0; j < 4; ++j) {
                int kv = kvq * 4 + j;
                int pg = (stid & 7) ^ (kv & 7);
                *reinterpret_cast<bf16x8*>(&Ks[kv * 64 + pg * 8]) = rs[j];
            }
        } else {
            int lg = kvq >> 1, half = kvq & 1;
#pragma unroll
            for (int jj = 0; jj < 8; ++jj) {
                int d = d0 + jj;
                int phys = lg ^ (d & 7);
                s16x4 pk = {r0[jj], r1[jj], r2[jj], r3[jj]};
                *reinterpret_cast<s16x4*>(&Vt[d * 128 + phys * 8 + half * 4]) = pk;
            }
        }
    };

    int ntiles = qt + 1;
    loadKV(0);
    for (int t = 0; t < ntiles; ++t) {
        __syncthreads();                 // prior tile's LDS reads done
        writeKV();
        __syncthreads();                 // publish Ks/Vt
        if (t + 1 < ntiles) loadKV(t + 1);   // lands under this tile's compute

        int kv0 = t * 128;
        // ---- QK^T: 16 MFMA ----
        f32x4 sf[8];
#pragma unroll
        for (int n = 0; n < 8; ++n) sf[n] = (f32x4){0.f, 0.f, 0.f, 0.f};
        __builtin_amdgcn_s_setprio(1);
#pragma unroll
        for (int n = 0; n < 8; ++n) {
            int row = n * 16 + r;
#pragma unroll
            for (int kt = 0; kt < 2; ++kt) {
                int gran = (kt * 4 + kq) ^ (row & 7);
                bf16x8 kf = *reinterpret_cast<bf16x8*>(&Ks[row * 64 + gran * 8]);
                sf[n] = MFMA16(qf[kt], kf, sf[n]);
            }
        }
        __builtin_amdgcn_s_setprio(0);

        // ---- online softmax over 128 cols (DPP 16-lane reductions) ----
        bool diag = (kv0 + 128 > q0);
        float alpha[4];
#pragma unroll
        for (int rr = 0; rr < 4; ++rr) {
            int qrow = q0 + w * 16 + kq * 4 + rr;
            float vals[8];
            float mx = mrow[rr];
#pragma unroll
            for (int n = 0; n < 8; ++n) {
                float v = sf[n][rr] * 0.125f;
                if (diag && (kv0 + n * 16 + r) > qrow) v = -INFINITY;
                vals[n] = v;
                mx = fmaxf(mx, v);
            }
            mx = dpp_max16(mx);
            float al = __expf(mrow[rr] - mx);
            float sum = 0.f;
#pragma unroll
            for (int n = 0; n < 8; ++n) {
                float p = __expf(vals[n] - mx);
                vals[n] = p;
                sum += p;
            }
            sum = dpp_sum16(sum);
            mrow[rr] = mx;
            lrow[rr] = lrow[rr] * al + sum;
            alpha[rr] = al;
#pragma unroll
            for (int n = 0; n < 8; ++n) Ps[w][kq * 4 + rr][n * 16 + r] = f2bf(vals[n]);
        }
#pragma unroll
        for (int n = 0; n < 4; ++n)
#pragma unroll
            for (int rr = 0; rr < 4; ++rr) of[n][rr] *= alpha[rr];

        // ---- PV: 16 MFMA ----
        __builtin_amdgcn_s_setprio(1);
#pragma unroll
        for (int kt = 0; kt < 4; ++kt) {
            bf16x8 pa = *reinterpret_cast<bf16x8*>(&Ps[w][r][kt * 32 + kq * 8]);
#pragma unroll
            for (int n = 0; n < 4; ++n) {
                int row = n * 16 + r;
                int gran = (kt * 4 + kq) ^ (row & 7);
                bf16x8 vf = *reinterpret_cast<bf16x8*>(&Vt[row * 128 + gran * 8]);
                of[n] = MFMA16(pa, vf, of[n]);
            }
        }
        __builtin_amdgcn_s_setprio(0);
    }

    // ---- epilogue ----
#pragma unroll
    for (int rr = 0; rr < 4; ++rr) {
        float inv = 1.0f / lrow[rr];
        int qrow = q0 + w * 16 + kq * 4 + rr;
        bf16* cb = ctx + (size_t)(b * TSEQ + qrow) * DM + h * 64;
#pragma unroll
        for (int n = 0; n < 4; ++n) cb[n * 16 + r] = (bf16)(of[n][rr] * inv);
    }
}

// ---------------- loss: merge per-chunk partials ----------------
__global__ __launch_bounds__(256) void loss_reduce_kernel(const float2* __restrict__ partials,
                                                          const float* __restrict__ logits,
                                                          const int* __restrict__ target,
                                                          float* __restrict__ nll) {
    int row = blockIdx.x, tid = threadIdx.x;
    const float2* pr = partials + (size_t)row * NCHUNK;
    float m = -INFINITY, s = 0.f;
    for (int c = tid; c < NCHUNK; c += 256) {
        float2 p = pr[c];
        if (p.x > m) { s = s * __expf(m - p.x) + p.y; m = p.x; }
        else         { s += p.y * __expf(p.x - m); }
    }
    __shared__ float sm[256], ssum[256];
    sm[tid] = m; ssum[tid] = s; __syncthreads();
    for (int o = 128; o; o >>= 1) {
        if (tid < o) {
            float m2 = sm[tid + o], s2 = ssum[tid + o];
            float mm = fmaxf(sm[tid], m2);
            ssum[tid] = ssum[tid] * __expf(sm[tid] - mm) + s2 * __expf(m2 - mm);
            sm[tid] = mm;
        }
        __syncthreads();
    }
    if (tid == 0) {
        float lse = sm[0] + logf(ssum[0]);
        nll[row] = lse - logits[(size_t)row * VOCAB + target[row]];
    }
}

__global__ void loss2_kernel(const float* __restrict__ nll, float* __restrict__ loss) {
    int tid = threadIdx.x;
    float s = 0.f;
    for (int i = tid; i < BT; i += 1024) s += nll[i];
    __shared__ float r[1024];
    r[tid] = s; __syncthreads();
    for (int o = 512; o; o >>= 1) { if (tid < o) r[tid] += r[tid + o]; __syncthreads(); }
    if (tid == 0) *loss = r[0] * (1.0f / BT);
}

// ---------------- launcher ----------------
extern "C" void kernel_launch(void* const* d_in, const int* in_sizes, int n_in,
                              void* d_out, int out_size, void* d_ws, size_t ws_size,
                              hipStream_t stream) {
    const int*   inp    = (const int*)  d_in[0];
    const int*   target = (const int*)  d_in[1];
    const float* wte    = (const float*)d_in[2];
    const float* wpe    = (const float*)d_in[3];
    const float* ln1_w  = (const float*)d_in[4];
    const float* ln1_b  = (const float*)d_in[5];
    const float* attn_w = (const float*)d_in[6];
    const float* attn_b = (const float*)d_in[7];
    const float* proj_w = (const float*)d_in[8];
    const float* proj_b = (const float*)d_in[9];
    const float* ln2_w  = (const float*)d_in[10];
    const float* ln2_b  = (const float*)d_in[11];
    const float* fc_w   = (const float*)d_in[12];
    const float* fc_b   = (const float*)d_in[13];
    const float* fc2_w  = (const float*)d_in[14];
    const float* fc2_b  = (const float*)d_in[15];
    const float* lnf_w  = (const float*)d_in[16];
    const float* lnf_b  = (const float*)d_in[17];
    float* out = (float*)d_out;

    char* p = (char*)d_ws;
    auto alloc = [&](size_t bytes) { char* q = p; p += (bytes + 255) & ~(size_t)255; return q; };
    float* x     = (float*)alloc((size_t)BT * DM * 4);
    float* nll   = (float*)alloc((size_t)BT * 4);
    bf16*  qkvb  = (bf16*) alloc((size_t)BT * 3 * DM * 2);
    bf16*  tmpb  = (bf16*) alloc((size_t)BT * DM * 2);
    bf16*  ctxb  = (bf16*) alloc((size_t)BT * DM * 2);
    bf16*  hb    = (bf16*) alloc((size_t)BT * 4 * DM * 2);
    bf16*  wteb  = (bf16*) alloc((size_t)VOCAB * DM * 2);
    bf16*  wqkvT = (bf16*) alloc((size_t)NLAYERS * 3 * DM * DM * 2);
    bf16*  wprojT= (bf16*) alloc((size_t)NLAYERS * DM * DM * 2);
    bf16*  wfcT  = (bf16*) alloc((size_t)NLAYERS * 4 * DM * DM * 2);
    bf16*  wfc2T = (bf16*) alloc((size_t)NLAYERS * 4 * DM * DM * 2);
    // loss partials (25.8 MB) alias the ctxb+hb region (31.5 MB, dead after layer loop)
    float2* partials = (float2*)ctxb;

    dim3 tb(32, 8);
    transpose_bf16_kernel<<<dim3(3 * DM / 32, DM / 32, NLAYERS), tb, 0, stream>>>(attn_w, wqkvT, DM, 3 * DM);
    transpose_bf16_kernel<<<dim3(DM / 32, DM / 32, NLAYERS), tb, 0, stream>>>(proj_w, wprojT, DM, DM);
    transpose_bf16_kernel<<<dim3(4 * DM / 32, DM / 32, NLAYERS), tb, 0, stream>>>(fc_w, wfcT, DM, 4 * DM);
    transpose_bf16_kernel<<<dim3(DM / 32, 4 * DM / 32, NLAYERS), tb, 0, stream>>>(fc2_w, wfc2T, 4 * DM, DM);
    {
        size_t n4 = (size_t)VOCAB * DM / 4;
        tobf16_kernel<<<(unsigned)((n4 + 255) / 256), 256, 0, stream>>>(wte, wteb, n4);
    }

    embed_kernel<<<BT * DM / 4 / 256, 256, 0, stream>>>(inp, wte, wpe, x);

    for (int i = 0; i < NLAYERS; ++i) {
        ln_kernel<<<BT / 4, 256, 0, stream>>>(x, ln1_w + i * DM, ln1_b + i * DM, tmpb);
        gemm_k<GF_OBF16, 0><<<dim3(BT / 128, 3 * DM / 128), 256, 0, stream>>>(
            tmpb, wqkvT + (size_t)i * 3 * DM * DM, attn_b + i * 3 * DM, nullptr,
            qkvb, nullptr, BT, 3 * DM, DM);
        flash_attn_kernel<<<dim3(TSEQ / 128, 4 * NHEADS), 512, 0, stream>>>(qkvb, ctxb);
        gemm_k<0, 1><<<dim3(BT / 128, DM / 128), 256, 0, stream>>>(
            ctxb, wprojT + (size_t)i * DM * DM, proj_b + i * DM, x,
            x, nullptr, BT, DM, DM);
        ln_kernel<<<BT / 4, 256, 0, stream>>>(x, ln2_w + i * DM, ln2_b + i * DM, tmpb);
        gemm_k<GF_GELU | GF_OBF16, 2><<<dim3(BT / 128, 4 * DM / 128), 256, 0, stream>>>(
            tmpb, wfcT + (size_t)i * 4 * DM * DM, fc_b + i * 4 * DM, nullptr,
            hb, nullptr, BT, 4 * DM, DM);
        gemm_k<0, 3><<<dim3(BT / 128, DM / 128), 256, 0, stream>>>(
            hb, wfc2T + (size_t)i * 4 * DM * DM, fc2_b + i * DM, x,
            x, nullptr, BT, DM, 4 * DM);
    }

    ln_kernel<<<BT / 4, 256, 0, stream>>>(x, lnf_w, lnf_b, tmpb);
    gemm_wide<GF_CLAMP | GF_PARTIAL, 4><<<dim3(BT / 128, (VOCAB + 255) / 256), 512, 0, stream>>>(
        tmpb, wteb, nullptr, nullptr, out, partials, BT, VOCAB, DM);
    loss_reduce_kernel<<<BT, 256, 0, stream>>>(partials, out, target, nll);
    loss2_kernel<<<1, 1024, 0, stream>>>(nll, out + (size_t)out_size - 1);
}

// Round 14
// 3619.786 us; speedup vs baseline: 1.1992x; 1.1135x over previous
//
#include <hip/hip_runtime.h>
#include <hip/hip_bf16.h>
#include <cmath>

#define NLAYERS 12
#define NHEADS  12
#define DM      768
#define VOCAB   50257
#define TSEQ    1024
#define BT      4096   // B*T
#define NCHUNK  786    // ceil(VOCAB/64) col-chunks for loss partials

typedef __attribute__((ext_vector_type(4))) float f32x4;
typedef __attribute__((ext_vector_type(8))) short bf16x8;
typedef __attribute__((ext_vector_type(4))) short s16x4;

typedef __hip_bfloat16 bf16;

#define MFMA16(a, b, c) __builtin_amdgcn_mfma_f32_16x16x32_bf16(a, b, c, 0, 0, 0)

// ---------------- helpers ----------------
__device__ __forceinline__ void gload16(const void* g, void* l) {
    __builtin_amdgcn_global_load_lds(
        (const __attribute__((address_space(1))) void*)g,
        (__attribute__((address_space(3))) void*)l, 16, 0, 0);
}

// raw s_barrier with compiler memory fences (no forced vmcnt(0) drain)
__device__ __forceinline__ void wg_barrier() {
    asm volatile("" ::: "memory");
    __builtin_amdgcn_s_barrier();
    asm volatile("" ::: "memory");
}

__device__ __forceinline__ float gelu_tanh(float v) {
    float u = 0.7978845608028654f * (v + 0.044715f * v * v * v);
    return 0.5f * v * (1.0f + tanhf(u));
}

__device__ __forceinline__ short f2bf(float f) {
    bf16 h = (bf16)f;
    return *reinterpret_cast<short*>(&h);
}

// ---- DPP 16-lane butterfly reductions (VALU-speed, no LDS/bpermute) ----
template<int CTRL>
__device__ __forceinline__ float dpp_mov(float x) {
    int i = __builtin_bit_cast(int, x);
    i = __builtin_amdgcn_mov_dpp(i, CTRL, 0xF, 0xF, false);
    return __builtin_bit_cast(float, i);
}
__device__ __forceinline__ float dpp_max16(float x) {
    x = fmaxf(x, dpp_mov<0xB1>(x));
    x = fmaxf(x, dpp_mov<0x4E>(x));
    x = fmaxf(x, dpp_mov<0x141>(x));
    x = fmaxf(x, dpp_mov<0x140>(x));
    return x;
}
__device__ __forceinline__ float dpp_sum16(float x) {
    x += dpp_mov<0xB1>(x);
    x += dpp_mov<0x4E>(x);
    x += dpp_mov<0x141>(x);
    x += dpp_mov<0x140>(x);
    return x;
}

struct ushort4s { short a, b, c, d; };

// ---------------- weight prep ----------------
__global__ void transpose_bf16_kernel(const float* __restrict__ in, bf16* __restrict__ out,
                                      int K, int N) {
    __shared__ float tile[32][33];
    size_t lofs = (size_t)blockIdx.z * K * N;
    int k0 = blockIdx.y * 32, n0 = blockIdx.x * 32;
    int tx = threadIdx.x, ty = threadIdx.y;      // 32x8
#pragma unroll
    for (int i = 0; i < 32; i += 8)
        tile[ty + i][tx] = in[lofs + (size_t)(k0 + ty + i) * N + n0 + tx];
    __syncthreads();
#pragma unroll
    for (int i = 0; i < 32; i += 8)
        out[lofs + (size_t)(n0 + ty + i) * K + k0 + tx] = (bf16)tile[tx][ty + i];
}

__global__ void tobf16_kernel(const float* __restrict__ in, bf16* __restrict__ out, size_t n4) {
    size_t i = (size_t)blockIdx.x * 256 + threadIdx.x;
    if (i < n4) {
        float4 f = reinterpret_cast<const float4*>(in)[i];
        s16x4 o = {f2bf(f.x), f2bf(f.y), f2bf(f.z), f2bf(f.w)};
        *reinterpret_cast<s16x4*>(out + i * 4) = o;
    }
}

// ---------------- embedding (fp32 residual stream, float4) ----------------
__global__ void embed_kernel(const int* __restrict__ inp, const float* __restrict__ wte,
                             const float* __restrict__ wpe, float* __restrict__ x) {
    int idx = blockIdx.x * 256 + threadIdx.x;    // over BT*DM/4
    int m = idx / (DM / 4), c4 = idx % (DM / 4);
    int tok = inp[m];
    int t = m & (TSEQ - 1);
    float4 a = reinterpret_cast<const float4*>(wte)[(size_t)tok * (DM / 4) + c4];
    float4 b = reinterpret_cast<const float4*>(wpe)[(size_t)t * (DM / 4) + c4];
    float4 o = {a.x + b.x, a.y + b.y, a.z + b.z, a.w + b.w};
    reinterpret_cast<float4*>(x)[idx] = o;
}

// ---------------- layernorm: one row per WAVE (no block sync) ----------------
__global__ __launch_bounds__(256) void ln_kernel(const float* __restrict__ x,
                                                 const float* __restrict__ w,
                                                 const float* __restrict__ b,
                                                 bf16* __restrict__ y) {
    int tid = threadIdx.x, wv = tid >> 6, lane = tid & 63;
    int row = blockIdx.x * 4 + wv;
    const float4* xr = reinterpret_cast<const float4*>(x + (size_t)row * DM);
    float4 v[3];
    float s = 0.f, q = 0.f;
#pragma unroll
    for (int j = 0; j < 3; ++j) {
        v[j] = xr[lane + 64 * j];
        s += v[j].x + v[j].y + v[j].z + v[j].w;
        q += v[j].x * v[j].x + v[j].y * v[j].y + v[j].z * v[j].z + v[j].w * v[j].w;
    }
#pragma unroll
    for (int o = 1; o < 64; o <<= 1) { s += __shfl_xor(s, o); q += __shfl_xor(q, o); }
    float mu  = s * (1.0f / DM);
    float var = q * (1.0f / DM) - mu * mu;
    float inv = rsqrtf(var + 1e-5f);
#pragma unroll
    for (int j = 0; j < 3; ++j) {
        int c4 = lane + 64 * j;
        float4 wv4 = reinterpret_cast<const float4*>(w)[c4];
        float4 bv4 = reinterpret_cast<const float4*>(b)[c4];
        ushort4s o;
        o.a = f2bf((v[j].x - mu) * inv * wv4.x + bv4.x);
        o.b = f2bf((v[j].y - mu) * inv * wv4.y + bv4.y);
        o.c = f2bf((v[j].z - mu) * inv * wv4.z + bv4.z);
        o.d = f2bf((v[j].w - mu) * inv * wv4.w + bv4.w);
        *reinterpret_cast<ushort4s*>(y + (size_t)row * DM + c4 * 4) = o;
    }
}

#define GF_GELU    1
#define GF_OBF16   2
#define GF_CLAMP   4
#define GF_PARTIAL 8

// ---------------- 128x128 GEMM, 3-buffer 2-ahead prefetch, counted vmcnt ----------------
template<int FLAGS, int TAG>
__global__ __launch_bounds__(256) void gemm_k(
    const bf16* __restrict__ A, const bf16* __restrict__ Bt,
    const float* __restrict__ bias, const float* __restrict__ resid,
    void* __restrict__ C, float2* __restrict__ partials,
    int M, int N, int K) {
    __shared__ short ldsA[3][128 * 32];
    __shared__ short ldsB[3][128 * 32];
    int tid = threadIdx.x;
    int lane = tid & 63, w = tid >> 6;
    int wm = w >> 1, wn = w & 1;
    int r = lane & 15, kq = lane >> 4;
    int bm = blockIdx.x * 128, bn = blockIdx.y * 128;

    f32x4 acc[4][4] = {};

    auto stage = [&](int buf, int kt) {
        int k0 = kt * 32;
#pragma unroll
        for (int i = 0; i < 2; ++i) {
            int chunk = i * 256 + tid;           // 16B chunk id = row*4 + dest granule
            int row = chunk >> 2;
            int gs = (chunk & 3) ^ ((row >> 1) & 3);   // swizzled source granule
            const bf16* ga = A + (size_t)(bm + row) * K + k0 + gs * 8;
            gload16(ga, &ldsA[buf][(i * 256 + w * 64) * 8]);
            int brow = bn + row;
            const bf16* gb = Bt + (size_t)brow * K + k0 + gs * 8;
            gload16(gb, &ldsB[buf][(i * 256 + w * 64) * 8]);
        }
    };
    auto compute = [&](int buf) {
        bf16x8 af[4], bfr[4];
#pragma unroll
        for (int m = 0; m < 4; ++m) {
            int row = wm * 64 + m * 16 + r;
            af[m] = *reinterpret_cast<bf16x8*>(&ldsA[buf][row * 32 + (kq ^ ((row >> 1) & 3)) * 8]);
        }
#pragma unroll
        for (int n = 0; n < 4; ++n) {
            int row = wn * 64 + n * 16 + r;
            bfr[n] = *reinterpret_cast<bf16x8*>(&ldsB[buf][row * 32 + (kq ^ ((row >> 1) & 3)) * 8]);
        }
        __builtin_amdgcn_s_setprio(1);
#pragma unroll
        for (int m = 0; m < 4; ++m)
#pragma unroll
            for (int n = 0; n < 4; ++n)
                acc[m][n] = MFMA16(af[m], bfr[n], acc[m][n]);
        __builtin_amdgcn_s_setprio(0);
    };

    const int NT = K / 32;
    stage(0, 0);
    stage(1, 1);
    for (int t = 0; t < NT; ++t) {
        if (t + 2 < NT) {
            stage((t + 2) % 3, t + 2);
            asm volatile("s_waitcnt vmcnt(8)" ::: "memory");   // tile t landed
        } else if (t + 1 < NT) {
            asm volatile("s_waitcnt vmcnt(4)" ::: "memory");
        } else {
            asm volatile("s_waitcnt vmcnt(0)" ::: "memory");
        }
        wg_barrier();                    // tile t resident for ALL waves
        compute(t % 3);
        asm volatile("s_waitcnt lgkmcnt(0)" ::: "memory");     // my reads done
        wg_barrier();                    // publish: buffer reusable
    }

    int row0 = bm + wm * 64, col0 = bn + wn * 64;
#pragma unroll
    for (int m = 0; m < 4; ++m) {
#pragma unroll
        for (int n = 0; n < 4; ++n) {
            int col = col0 + n * 16 + r;
#pragma unroll
            for (int rr = 0; rr < 4; ++rr) {
                int row = row0 + m * 16 + kq * 4 + rr;
                float v = acc[m][n][rr];
                if (bias) v += bias[col];
                if (FLAGS & GF_GELU) v = gelu_tanh(v);
                if (resid) v += resid[(size_t)row * N + col];
                if (FLAGS & GF_OBF16) ((bf16*)C)[(size_t)row * N + col] = (bf16)v;
                else                  ((float*)C)[(size_t)row * N + col] = v;
            }
        }
    }
}

// ---------------- 64x128 GEMM (proj / fc2: N=768) -- 2x grid for occupancy ----------------
// 4 waves, each 64x32 (acc 32 VGPR). 3-buffer 2-ahead, 3 loads/thread/tile ->
// vmcnt(6)/(3)/(0). LDS 36 KB -> up to 4 blocks/CU; grid 64x6 = 384 blocks.
template<int FLAGS, int TAG>
__global__ __launch_bounds__(256) void gemm_k64(
    const bf16* __restrict__ A, const bf16* __restrict__ Bt,
    const float* __restrict__ bias, const float* __restrict__ resid,
    void* __restrict__ C, float2* __restrict__ partials,
    int M, int N, int K) {
    __shared__ short ldsA[3][64 * 32];
    __shared__ short ldsB[3][128 * 32];
    int tid = threadIdx.x;
    int lane = tid & 63, w = tid >> 6;           // 4 waves, wave w: cols w*32..+31
    int r = lane & 15, kq = lane >> 4;
    int bm = blockIdx.x * 64, bn = blockIdx.y * 128;

    f32x4 acc[4][2] = {};

    auto stage = [&](int buf, int kt) {
        int k0 = kt * 32;
        {   // A tile: 64 rows x 4 granules = 256 chunks, 1/thread
            int row = tid >> 2;
            int gs = (tid & 3) ^ ((row >> 1) & 3);
            gload16(A + (size_t)(bm + row) * K + k0 + gs * 8, &ldsA[buf][tid * 8]);
        }
#pragma unroll
        for (int i = 0; i < 2; ++i) {            // B tile: 128 rows x 4 = 512 chunks, 2/thread
            int chunk = i * 256 + tid;
            int row = chunk >> 2;
            int gs = (chunk & 3) ^ ((row >> 1) & 3);
            gload16(Bt + (size_t)(bn + row) * K + k0 + gs * 8, &ldsB[buf][chunk * 8]);
        }
    };
    auto compute = [&](int buf) {
        bf16x8 af[4], bfr[2];
#pragma unroll
        for (int m = 0; m < 4; ++m) {
            int row = m * 16 + r;
            af[m] = *reinterpret_cast<bf16x8*>(&ldsA[buf][row * 32 + (kq ^ ((row >> 1) & 3)) * 8]);
        }
#pragma unroll
        for (int n = 0; n < 2; ++n) {
            int row = w * 32 + n * 16 + r;
            bfr[n] = *reinterpret_cast<bf16x8*>(&ldsB[buf][row * 32 + (kq ^ ((row >> 1) & 3)) * 8]);
        }
        __builtin_amdgcn_s_setprio(1);
#pragma unroll
        for (int m = 0; m < 4; ++m)
#pragma unroll
            for (int n = 0; n < 2; ++n)
                acc[m][n] = MFMA16(af[m], bfr[n], acc[m][n]);
        __builtin_amdgcn_s_setprio(0);
    };

    const int NT = K / 32;
    stage(0, 0);
    stage(1, 1);
    for (int t = 0; t < NT; ++t) {
        if (t + 2 < NT) {
            stage((t + 2) % 3, t + 2);
            asm volatile("s_waitcnt vmcnt(6)" ::: "memory");   // tile t landed
        } else if (t + 1 < NT) {
            asm volatile("s_waitcnt vmcnt(3)" ::: "memory");
        } else {
            asm volatile("s_waitcnt vmcnt(0)" ::: "memory");
        }
        wg_barrier();
        compute(t % 3);
        asm volatile("s_waitcnt lgkmcnt(0)" ::: "memory");
        wg_barrier();
    }

    int col0 = bn + w * 32;
#pragma unroll
    for (int m = 0; m < 4; ++m) {
#pragma unroll
        for (int n = 0; n < 2; ++n) {
            int col = col0 + n * 16 + r;
#pragma unroll
            for (int rr = 0; rr < 4; ++rr) {
                int row = bm + m * 16 + kq * 4 + rr;
                float v = acc[m][n][rr];
                if (bias) v += bias[col];
                if (FLAGS & GF_GELU) v = gelu_tanh(v);
                if (resid) v += resid[(size_t)row * N + col];
                if (FLAGS & GF_OBF16) ((bf16*)C)[(size_t)row * N + col] = (bf16)v;
                else                  ((float*)C)[(size_t)row * N + col] = v;
            }
        }
    }
}

// ---------------- 128x256 GEMM, 8 waves x 64x64, 3-buffer 2-ahead (lm_head) ----------------
template<int FLAGS, int TAG>
__global__ __launch_bounds__(512, 4) void gemm_wide(
    const bf16* __restrict__ A, const bf16* __restrict__ Bt,
    const float* __restrict__ bias, const float* __restrict__ resid,
    void* __restrict__ C, float2* __restrict__ partials,
    int M, int N, int K) {
    __shared__ short ldsA[3][128 * 32];          // 3 x 8 KB
    __shared__ short ldsB[3][256 * 32];          // 3 x 16 KB
    int tid = threadIdx.x;                       // 0..511
    int lane = tid & 63, w = tid >> 6;
    int wm = w >> 2, wn = w & 3;                 // 2M x 4N waves, 64x64 each
    int r = lane & 15, kq = lane >> 4;
    int bm = blockIdx.x * 128, bn = blockIdx.y * 256;

    f32x4 acc[4][4] = {};

    auto stage = [&](int buf, int kt) {
        int k0 = kt * 32;
        {   // A tile: 512 chunks, 1 per thread
            int row = tid >> 2;
            int gs = (tid & 3) ^ ((row >> 1) & 3);
            gload16(A + (size_t)(bm + row) * K + k0 + gs * 8, &ldsA[buf][tid * 8]);
        }
#pragma unroll
        for (int i = 0; i < 2; ++i) {            // B tile: 1024 chunks, 2 per thread
            int chunk = i * 512 + tid;
            int row = chunk >> 2;
            int gs = (chunk & 3) ^ ((row >> 1) & 3);
            int grow = bn + row;
            if (FLAGS & GF_CLAMP) grow = min(grow, N - 1);
            gload16(Bt + (size_t)grow * K + k0 + gs * 8, &ldsB[buf][chunk * 8]);
        }
    };
    auto compute = [&](int buf) {
        bf16x8 af[4], bfr[4];
#pragma unroll
        for (int m = 0; m < 4; ++m) {
            int row = wm * 64 + m * 16 + r;
            af[m] = *reinterpret_cast<bf16x8*>(&ldsA[buf][row * 32 + (kq ^ ((row >> 1) & 3)) * 8]);
        }
#pragma unroll
        for (int n = 0; n < 4; ++n) {
            int row = wn * 64 + n * 16 + r;
            bfr[n] = *reinterpret_cast<bf16x8*>(&ldsB[buf][row * 32 + (kq ^ ((row >> 1) & 3)) * 8]);
        }
        __builtin_amdgcn_s_setprio(1);
#pragma unroll
        for (int m = 0; m < 4; ++m)
#pragma unroll
            for (int n = 0; n < 4; ++n)
                acc[m][n] = MFMA16(af[m], bfr[n], acc[m][n]);
        __builtin_amdgcn_s_setprio(0);
    };

    const int NT = K / 32;                       // 24
    stage(0, 0);
    stage(1, 1);
    for (int t = 0; t < NT; ++t) {
        if (t + 2 < NT) {
            stage((t + 2) % 3, t + 2);
            asm volatile("s_waitcnt vmcnt(6)" ::: "memory");   // tile t landed
        } else if (t + 1 < NT) {
            asm volatile("s_waitcnt vmcnt(3)" ::: "memory");
        } else {
            asm volatile("s_waitcnt vmcnt(0)" ::: "memory");
        }
        wg_barrier();
        compute(t % 3);
        asm volatile("s_waitcnt lgkmcnt(0)" ::: "memory");
        wg_barrier();
    }

    int row0 = bm + wm * 64, col0 = bn + wn * 64;
#pragma unroll
    for (int m = 0; m < 4; ++m) {
#pragma unroll
        for (int n = 0; n < 4; ++n) {
            int col = col0 + n * 16 + r;
            if (col < N) {
#pragma unroll
                for (int rr = 0; rr < 4; ++rr) {
                    int row = row0 + m * 16 + kq * 4 + rr;
                    float v = acc[m][n][rr];
                    if (bias) v += bias[col];
                    if (FLAGS & GF_GELU) v = gelu_tanh(v);
                    if (resid) v += resid[(size_t)row * N + col];
                    if (FLAGS & GF_OBF16) ((bf16*)C)[(size_t)row * N + col] = (bf16)v;
                    else                  ((float*)C)[(size_t)row * N + col] = v;
                }
            }
        }
    }

    if (FLAGS & GF_PARTIAL) {
        int chunk = (bn >> 6) + wn;              // 64-col chunk index
        if (chunk < NCHUNK) {
#pragma unroll
            for (int m = 0; m < 4; ++m) {
#pragma unroll
                for (int rr = 0; rr < 4; ++rr) {
                    float vals[4], mx = -INFINITY;
#pragma unroll
                    for (int n = 0; n < 4; ++n) {
                        int col = col0 + n * 16 + r;
                        float v = (col < N) ? acc[m][n][rr] : -INFINITY;
                        vals[n] = v;
                        mx = fmaxf(mx, v);
                    }
                    mx = dpp_max16(mx);
                    float sum = 0.f;
#pragma unroll
                    for (int n = 0; n < 4; ++n)
                        if (vals[n] > -INFINITY) sum += __expf(vals[n] - mx);
                    sum = dpp_sum16(sum);
                    if (r == 0) {
                        int row = row0 + m * 16 + kq * 4 + rr;
                        partials[(size_t)row * NCHUNK + chunk] = make_float2(mx, sum);
                    }
                }
            }
        }
    }
}

// ---------------- flash attention: QBLK=128, 8 waves, reg-staged K/V, DPP softmax ----------------
__global__ __launch_bounds__(512, 4) void flash_attn_kernel(const bf16* __restrict__ qkv,
                                                            bf16* __restrict__ ctx) {
    __shared__ short Ks[128 * 64];       // K tile [kv][64 d], granule ^= kv&7
    __shared__ short Vt[64 * 128];       // V^T tile [d][128 kv], granule ^= d&7
    __shared__ short Ps[8][16][132];     // per-wave P tile [qrow][kv], padded

    int tid = threadIdx.x, lane = tid & 63, w = tid >> 6;   // 8 waves
    int r = lane & 15, kq = lane >> 4;
    int qt = (int)gridDim.x - 1 - (int)blockIdx.x;           // longest first
    int q0 = qt * 128;
    int bh = blockIdx.y;
    int b = bh / NHEADS, h = bh % NHEADS;
    const int RS = 3 * DM;

    const bf16* qbase = qkv + (size_t)(b * TSEQ + q0 + w * 16 + r) * RS + h * 64;
    bf16x8 qf[2];
    qf[0] = *reinterpret_cast<const bf16x8*>(qbase + kq * 8);
    qf[1] = *reinterpret_cast<const bf16x8*>(qbase + 32 + kq * 8);

    f32x4 of[4] = {};
    float mrow[4] = {-INFINITY, -INFINITY, -INFINITY, -INFINITY};
    float lrow[4] = {};

    int stid = tid & 255;
    int kvq = stid >> 3;                 // 0..31 -> kv rows kvq*4..+3
    int d0 = (stid & 7) * 8;
    bool isK = tid < 256;
    const bf16* sb0 = qkv + (size_t)(b * TSEQ) * RS + (isK ? DM : 2 * DM) + h * 64;
    bf16x8 r0, r1, r2, r3;

    auto loadKV = [&](int t) {
        const bf16* p = sb0 + (size_t)(t * 128 + kvq * 4) * RS + d0;
        r0 = *reinterpret_cast<const bf16x8*>(p);
        r1 = *reinterpret_cast<const bf16x8*>(p + RS);
        r2 = *reinterpret_cast<const bf16x8*>(p + 2 * RS);
        r3 = *reinterpret_cast<const bf16x8*>(p + 3 * RS);
    };
    auto writeKV = [&]() {
        if (isK) {
            bf16x8 rs[4] = {r0, r1, r2, r3};
#pragma unroll
            for (int j = 0; j < 4; ++j) {
                int kv = kvq * 4 + j;
                int pg = (stid & 7) ^ (kv & 7);
                *reinterpret_cast<bf16x8*>(&Ks[kv * 64 + pg * 8]) = rs[j];
            }
        } else {
            int lg = kvq >> 1, half = kvq & 1;
#pragma unroll
            for (int jj = 0; jj < 8; ++jj) {
                int d = d0 + jj;
                int phys = lg ^ (d & 7);
                s16x4 pk = {r0[jj], r1[jj], r2[jj], r3[jj]};
                *reinterpret_cast<s16x4*>(&Vt[d * 128 + phys * 8 + half * 4]) = pk;
            }
        }
    };

    int ntiles = qt + 1;
    loadKV(0);
    for (int t = 0; t < ntiles; ++t) {
        __syncthreads();                 // prior tile's LDS reads done
        writeKV();
        __syncthreads();                 // publish Ks/Vt
        if (t + 1 < ntiles) loadKV(t + 1);   // lands under this tile's compute

        int kv0 = t * 128;
        // ---- QK^T: 16 MFMA ----
        f32x4 sf[8];
#pragma unroll
        for (int n = 0; n < 8; ++n) sf[n] = (f32x4){0.f, 0.f, 0.f, 0.f};
        __builtin_amdgcn_s_setprio(1);
#pragma unroll
        for (int n = 0; n < 8; ++n) {
            int row = n * 16 + r;
#pragma unroll
            for (int kt = 0; kt < 2; ++kt) {
                int gran = (kt * 4 + kq) ^ (row & 7);
                bf16x8 kf = *reinterpret_cast<bf16x8*>(&Ks[row * 64 + gran * 8]);
                sf[n] = MFMA16(qf[kt], kf, sf[n]);
            }
        }
        __builtin_amdgcn_s_setprio(0);

        // ---- online softmax over 128 cols (DPP 16-lane reductions) ----
        bool diag = (kv0 + 128 > q0);
        float alpha[4];
#pragma unroll
        for (int rr = 0; rr < 4; ++rr) {
            int qrow = q0 + w * 16 + kq * 4 + rr;
            float vals[8];
            float mx = mrow[rr];
#pragma unroll
            for (int n = 0; n < 8; ++n) {
                float v = sf[n][rr] * 0.125f;
                if (diag && (kv0 + n * 16 + r) > qrow) v = -INFINITY;
                vals[n] = v;
                mx = fmaxf(mx, v);
            }
            mx = dpp_max16(mx);
            float al = __expf(mrow[rr] - mx);
            float sum = 0.f;
#pragma unroll
            for (int n = 0; n < 8; ++n) {
                float p = __expf(vals[n] - mx);
                vals[n] = p;
                sum += p;
            }
            sum = dpp_sum16(sum);
            mrow[rr] = mx;
            lrow[rr] = lrow[rr] * al + sum;
            alpha[rr] = al;
#pragma unroll
            for (int n = 0; n < 8; ++n) Ps[w][kq * 4 + rr][n * 16 + r] = f2bf(vals[n]);
        }
#pragma unroll
        for (int n = 0; n < 4; ++n)
#pragma unroll
            for (int rr = 0; rr < 4; ++rr) of[n][rr] *= alpha[rr];

        // ---- PV: 16 MFMA ----
        __builtin_amdgcn_s_setprio(1);
#pragma unroll
        for (int kt = 0; kt < 4; ++kt) {
            bf16x8 pa = *reinterpret_cast<bf16x8*>(&Ps[w][r][kt * 32 + kq * 8]);
#pragma unroll
            for (int n = 0; n < 4; ++n) {
                int row = n * 16 + r;
                int gran = (kt * 4 + kq) ^ (row & 7);
                bf16x8 vf = *reinterpret_cast<bf16x8*>(&Vt[row * 128 + gran * 8]);
                of[n] = MFMA16(pa, vf, of[n]);
            }
        }
        __builtin_amdgcn_s_setprio(0);
    }

    // ---- epilogue ----
#pragma unroll
    for (int rr = 0; rr < 4; ++rr) {
        float inv = 1.0f / lrow[rr];
        int qrow = q0 + w * 16 + kq * 4 + rr;
        bf16* cb = ctx + (size_t)(b * TSEQ + qrow) * DM + h * 64;
#pragma unroll
        for (int n = 0; n < 4; ++n) cb[n * 16 + r] = (bf16)(of[n][rr] * inv);
    }
}

// ---------------- loss: merge per-chunk partials ----------------
__global__ __launch_bounds__(256) void loss_reduce_kernel(const float2* __restrict__ partials,
                                                          const float* __restrict__ logits,
                                                          const int* __restrict__ target,
                                                          float* __restrict__ nll) {
    int row = blockIdx.x, tid = threadIdx.x;
    const float2* pr = partials + (size_t)row * NCHUNK;
    float m = -INFINITY, s = 0.f;
    for (int c = tid; c < NCHUNK; c += 256) {
        float2 p = pr[c];
        if (p.x > m) { s = s * __expf(m - p.x) + p.y; m = p.x; }
        else         { s += p.y * __expf(p.x - m); }
    }
    __shared__ float sm[256], ssum[256];
    sm[tid] = m; ssum[tid] = s; __syncthreads();
    for (int o = 128; o; o >>= 1) {
        if (tid < o) {
            float m2 = sm[tid + o], s2 = ssum[tid + o];
            float mm = fmaxf(sm[tid], m2);
            ssum[tid] = ssum[tid] * __expf(sm[tid] - mm) + s2 * __expf(m2 - mm);
            sm[tid] = mm;
        }
        __syncthreads();
    }
    if (tid == 0) {
        float lse = sm[0] + logf(ssum[0]);
        nll[row] = lse - logits[(size_t)row * VOCAB + target[row]];
    }
}

__global__ void loss2_kernel(const float* __restrict__ nll, float* __restrict__ loss) {
    int tid = threadIdx.x;
    float s = 0.f;
    for (int i = tid; i < BT; i += 1024) s += nll[i];
    __shared__ float r[1024];
    r[tid] = s; __syncthreads();
    for (int o = 512; o; o >>= 1) { if (tid < o) r[tid] += r[tid + o]; __syncthreads(); }
    if (tid == 0) *loss = r[0] * (1.0f / BT);
}

// ---------------- launcher ----------------
extern "C" void kernel_launch(void* const* d_in, const int* in_sizes, int n_in,
                              void* d_out, int out_size, void* d_ws, size_t ws_size,
                              hipStream_t stream) {
    const int*   inp    = (const int*)  d_in[0];
    const int*   target = (const int*)  d_in[1];
    const float* wte    = (const float*)d_in[2];
    const float* wpe    = (const float*)d_in[3];
    const float* ln1_w  = (const float*)d_in[4];
    const float* ln1_b  = (const float*)d_in[5];
    const float* attn_w = (const float*)d_in[6];
    const float* attn_b = (const float*)d_in[7];
    const float* proj_w = (const float*)d_in[8];
    const float* proj_b = (const float*)d_in[9];
    const float* ln2_w  = (const float*)d_in[10];
    const float* ln2_b  = (const float*)d_in[11];
    const float* fc_w   = (const float*)d_in[12];
    const float* fc_b   = (const float*)d_in[13];
    const float* fc2_w  = (const float*)d_in[14];
    const float* fc2_b  = (const float*)d_in[15];
    const float* lnf_w  = (const float*)d_in[16];
    const float* lnf_b  = (const float*)d_in[17];
    float* out = (float*)d_out;

    char* p = (char*)d_ws;
    auto alloc = [&](size_t bytes) { char* q = p; p += (bytes + 255) & ~(size_t)255; return q; };
    float* x     = (float*)alloc((size_t)BT * DM * 4);
    float* nll   = (float*)alloc((size_t)BT * 4);
    bf16*  qkvb  = (bf16*) alloc((size_t)BT * 3 * DM * 2);
    bf16*  tmpb  = (bf16*) alloc((size_t)BT * DM * 2);
    bf16*  ctxb  = (bf16*) alloc((size_t)BT * DM * 2);
    bf16*  hb    = (bf16*) alloc((size_t)BT * 4 * DM * 2);
    bf16*  wteb  = (bf16*) alloc((size_t)VOCAB * DM * 2);
    bf16*  wqkvT = (bf16*) alloc((size_t)NLAYERS * 3 * DM * DM * 2);
    bf16*  wprojT= (bf16*) alloc((size_t)NLAYERS * DM * DM * 2);
    bf16*  wfcT  = (bf16*) alloc((size_t)NLAYERS * 4 * DM * DM * 2);
    bf16*  wfc2T = (bf16*) alloc((size_t)NLAYERS * 4 * DM * DM * 2);
    // loss partials (25.8 MB) alias the ctxb+hb region (31.5 MB, dead after layer loop)
    float2* partials = (float2*)ctxb;

    dim3 tb(32, 8);
    transpose_bf16_kernel<<<dim3(3 * DM / 32, DM / 32, NLAYERS), tb, 0, stream>>>(attn_w, wqkvT, DM, 3 * DM);
    transpose_bf16_kernel<<<dim3(DM / 32, DM / 32, NLAYERS), tb, 0, stream>>>(proj_w, wprojT, DM, DM);
    transpose_bf16_kernel<<<dim3(4 * DM / 32, DM / 32, NLAYERS), tb, 0, stream>>>(fc_w, wfcT, DM, 4 * DM);
    transpose_bf16_kernel<<<dim3(DM / 32, 4 * DM / 32, NLAYERS), tb, 0, stream>>>(fc2_w, wfc2T, 4 * DM, DM);
    {
        size_t n4 = (size_t)VOCAB * DM / 4;
        tobf16_kernel<<<(unsigned)((n4 + 255) / 256), 256, 0, stream>>>(wte, wteb, n4);
    }

    embed_kernel<<<BT * DM / 4 / 256, 256, 0, stream>>>(inp, wte, wpe, x);

    for (int i = 0; i < NLAYERS; ++i) {
        ln_kernel<<<BT / 4, 256, 0, stream>>>(x, ln1_w + i * DM, ln1_b + i * DM, tmpb);
        gemm_k<GF_OBF16, 0><<<dim3(BT / 128, 3 * DM / 128), 256, 0, stream>>>(
            tmpb, wqkvT + (size_t)i * 3 * DM * DM, attn_b + i * 3 * DM, nullptr,
            qkvb, nullptr, BT, 3 * DM, DM);
        flash_attn_kernel<<<dim3(TSEQ / 128, 4 * NHEADS), 512, 0, stream>>>(qkvb, ctxb);
        gemm_k64<0, 1><<<dim3(BT / 64, DM / 128), 256, 0, stream>>>(
            ctxb, wprojT + (size_t)i * DM * DM, proj_b + i * DM, x,
            x, nullptr, BT, DM, DM);
        ln_kernel<<<BT / 4, 256, 0, stream>>>(x, ln2_w + i * DM, ln2_b + i * DM, tmpb);
        gemm_k<GF_GELU | GF_OBF16, 2><<<dim3(BT / 128, 4 * DM / 128), 256, 0, stream>>>(
            tmpb, wfcT + (size_t)i * 4 * DM * DM, fc_b + i * 4 * DM, nullptr,
            hb, nullptr, BT, 4 * DM, DM);
        gemm_k64<0, 3><<<dim3(BT / 64, DM / 128), 256, 0, stream>>>(
            hb, wfc2T + (size_t)i * 4 * DM * DM, fc2_b + i * DM, x,
            x, nullptr, BT, DM, 4 * DM);
    }

    ln_kernel<<<BT / 4, 256, 0, stream>>>(x, lnf_w, lnf_b, tmpb);
    gemm_wide<GF_CLAMP | GF_PARTIAL, 4><<<dim3(BT / 128, (VOCAB + 255) / 256), 512, 0, stream>>>(
        tmpb, wteb, nullptr, nullptr, out, partials, BT, VOCAB, DM);
    loss_reduce_kernel<<<BT, 256, 0, stream>>>(partials, out, target, nll);
    loss2_kernel<<<1, 1024, 0, stream>>>(nll, out + (size_t)out_size - 1);
}